// Round 1
// baseline (361.905 us; speedup 1.0000x reference)
//
#include <hip/hip_runtime.h>
#include <math.h>

#define NB 256
#define SEQ 65536
#define NP 2047
#define NPM 2046
#define KPAD 2048  // gemm K padded (bf16 operands zero-filled at k=2046,2047)
#define LEN1 2047
#define LEN2 1023
#define LEN3 511
#define C1 32
#define C2 64
#define C3 128
#define NPART 2048
#define LPAD 514   // h2T rows: pos -1 .. 512 (zero-padded ends)

// workspace offsets (floats). Region timeline:
//   Y2: gemm Wb (bf16) -> h1raw/h1 (conv1f pooled out, bn1 in-place) -> h2T (bf16, p2bf out)
//   Y1: pmaxT (conv2 pooled-raw out) only — y1/y3t eliminated (stats fused, conv3 recomputed)
//   DMAX: dmax bf16 [b][KPAD]
#define OFF_X3   0
#define SZ_X3    (NB*3*NP)
#define OFF_DMAX (OFF_X3 + SZ_X3)
#define SZ_DMAX  (NB*NPM)
#define OFF_Y1   (OFF_DMAX + SZ_DMAX)
#define SZ_Y1    (NB*C1*LEN1)
#define OFF_Y2   (OFF_Y1 + SZ_Y1)
#define SZ_Y2    (NB*C2*LEN2)
#define OFF_S1   (OFF_Y2 + SZ_Y2)
#define OFF_S2   (OFF_S1 + 2*C1)
#define OFF_S3   (OFF_S2 + 2*C2)
#define OFF_W2C  (OFF_S3 + 2*C3)
#define OFF_W3B  (OFF_W2C + C1*C2*3)   // conv3 weights bf16 [tap][c][i]
#define OFF_PS   (OFF_W3B + C2*C3*3)
#define OFF_PQ   (OFF_PS + C3*NPART)
#define OFF_WB   OFF_Y2   // gemm W bf16 [NP][KPAD] (dead after gemm)
#define OFF_H1   OFF_Y2   // pooled raw conv1 activations [b][i][m], m<LEN2 (bn1 applied in-place)
#define OFF_H2T  OFF_Y2   // bf16 [b][LPAD][C2] (h1 dead after conv2)
#define OFF_PMAX OFF_Y1   // conv2 pooled-raw out [b][m][c], m<LEN3

typedef __attribute__((ext_vector_type(8))) short short8;
typedef __attribute__((ext_vector_type(4))) float f32x4;

__device__ inline short f2bf(float f){
  union { float f; unsigned u; } x; x.f = f;
  unsigned r = x.u + 0x7FFF + ((x.u >> 16) & 1);   // RNE; inputs are normal finite
  return (short)(r >> 16);
}

#define ACCS16(X) X(0) X(1) X(2) X(3) X(4) X(5) X(6) X(7) \
                  X(8) X(9) X(10) X(11) X(12) X(13) X(14) X(15)
#define ACCS32(X) ACCS16(X) X(16) X(17) X(18) X(19) X(20) X(21) X(22) X(23) \
                  X(24) X(25) X(26) X(27) X(28) X(29) X(30) X(31)
#define HS34(X) X(0) X(1) X(2) X(3) X(4) X(5) X(6) X(7) X(8) X(9) X(10) X(11) \
                X(12) X(13) X(14) X(15) X(16) X(17) X(18) X(19) X(20) X(21) \
                X(22) X(23) X(24) X(25) X(26) X(27) X(28) X(29) X(30) X(31) X(32) X(33)
#define POOL16(X) X(0,0,1) X(1,2,3) X(2,4,5) X(3,6,7) X(4,8,9) X(5,10,11) X(6,12,13) X(7,14,15) \
                  X(8,16,17) X(9,18,19) X(10,20,21) X(11,22,23) X(12,24,25) X(13,26,27) X(14,28,29) X(15,30,31)

#define RED6(v) v += __shfl_xor(v,32,64); v += __shfl_xor(v,16,64); \
                v += __shfl_xor(v, 8,64); v += __shfl_xor(v, 4,64); \
                v += __shfl_xor(v, 2,64); v += __shfl_xor(v, 1,64);
#define RED4L(v) v += __shfl_xor(v,1,64); v += __shfl_xor(v,2,64); \
                 v += __shfl_xor(v,4,64); v += __shfl_xor(v,8,64);

// fp32 conv2 K-loop macros (R13 form — SMEM grouped x2)
#define HLA(j) float hh##j = hpA[j];
#define HLB(j) float gg##j = hpB[j];
#define CFA(p,j0,j1,j2) acc##p = fmaf(w0a_, hh##j0, acc##p); \
                        acc##p = fmaf(w1a_, hh##j1, acc##p); \
                        acc##p = fmaf(w2a_, hh##j2, acc##p);
#define CFB(p,j0,j1,j2) acc##p = fmaf(w0b_, gg##j0, acc##p); \
                        acc##p = fmaf(w1b_, gg##j1, acc##p); \
                        acc##p = fmaf(w2b_, gg##j2, acc##p);
#define CONVSTEPS(CF_) CF_(0,0,1,2)    CF_(1,1,2,3)    CF_(2,2,3,4)    CF_(3,3,4,5) \
              CF_(4,4,5,6)    CF_(5,5,6,7)    CF_(6,6,7,8)    CF_(7,7,8,9) \
              CF_(8,8,9,10)   CF_(9,9,10,11)  CF_(10,10,11,12) CF_(11,11,12,13) \
              CF_(12,12,13,14) CF_(13,13,14,15) CF_(14,14,15,16) CF_(15,15,16,17) \
              CF_(16,16,17,18) CF_(17,17,18,19) CF_(18,18,19,20) CF_(19,19,20,21) \
              CF_(20,20,21,22) CF_(21,21,22,23) CF_(22,22,23,24) CF_(23,23,24,25) \
              CF_(24,24,25,26) CF_(25,25,26,27) CF_(26,26,27,28) CF_(27,27,28,29) \
              CF_(28,28,29,30) CF_(29,29,30,31) CF_(30,30,31,32) CF_(31,31,32,33)

// MFMA conv3 tile grid: (lt, ct) in 4x4
#define TILES(X) X(0,0) X(0,1) X(0,2) X(0,3) X(1,0) X(1,1) X(1,2) X(1,3) \
                 X(2,0) X(2,1) X(2,2) X(2,3) X(3,0) X(3,1) X(3,2) X(3,3)

// ---------------- K1: patch mean/std + dmax (bf16, [b][KPAD]) + x3-ch2 bias init ----------------
__global__ __launch_bounds__(256) void k_patch(const float* __restrict__ x, const float* __restrict__ c1b,
                                               float* __restrict__ ws){
  float* x3    = ws + OFF_X3;
  short* dmaxB = (short*)(ws + OFF_DMAX);   // bf16 [NB][KPAD], zero-padded k>=NPM
  int b = blockIdx.y;
  int chunk = blockIdx.x;              // 0..31, 2048 floats each
  const float* xr = x + (size_t)b*SEQ + chunk*2048;
  __shared__ float Ss[65], Qs[65], Dm[65];
  int w = threadIdx.x >> 6;
  int l = threadIdx.x & 63;
  #pragma unroll
  for (int i=0;i<2;i++){
    int seg = w*2 + i;
    int off = seg*256;
    float4 A = *(const float4*)(xr + off + l*4);
    float4 Bh = make_float4(0.f,0.f,0.f,0.f);
    if (l >= 56){
      int g = chunk*2048 + off + 256 + (l-56)*4;
      if (g + 3 < SEQ) Bh = *(const float4*)(xr + off + 256 + (l-56)*4);
    }
    int src = (l+8) & 63;
    float p0 = __shfl(A.x, src, 64), p1 = __shfl(A.y, src, 64),
          p2 = __shfl(A.z, src, 64), p3 = __shfl(A.w, src, 64);
    if (l >= 56){ p0=Bh.x; p1=Bh.y; p2=Bh.z; p3=Bh.w; }
    float s = (A.x+A.y)+(A.z+A.w);
    float q = fmaf(A.x,A.x, fmaf(A.y,A.y, fmaf(A.z,A.z, A.w*A.w)));
    float d = fmaxf(fmaxf(p0-A.x, p1-A.y), fmaxf(p2-A.z, p3-A.w));
    #pragma unroll
    for (int o=1;o<8;o<<=1){
      s += __shfl_xor(s,o,64);
      q += __shfl_xor(q,o,64);
      d  = fmaxf(d, __shfl_xor(d,o,64));
    }
    if ((l&7)==0){ int m = seg*8 + (l>>3); Ss[m]=s; Qs[m]=q; Dm[m]=d; }
  }
  if (w==0){
    float s=0.f,q=0.f,d=-1e30f;
    if (l < 8){
      int g = chunk*2048 + 2048 + l*4;
      if (g+3 < SEQ){
        float4 A = *(const float4*)(xr + 2048 + l*4);
        float4 P = make_float4(0.f,0.f,0.f,0.f);
        if (g+35 < SEQ) P = *(const float4*)(xr + 2048 + 32 + l*4);
        s = (A.x+A.y)+(A.z+A.w);
        q = fmaf(A.x,A.x, fmaf(A.y,A.y, fmaf(A.z,A.z, A.w*A.w)));
        d = fmaxf(fmaxf(P.x-A.x, P.y-A.y), fmaxf(P.z-A.z, P.w-A.w));
      }
    }
    #pragma unroll
    for (int o=1;o<8;o<<=1){
      s += __shfl_xor(s,o,64);
      q += __shfl_xor(q,o,64);
      d  = fmaxf(d, __shfl_xor(d,o,64));
    }
    if (l==0){ Ss[64]=s; Qs[64]=q; Dm[64]=d; }
  }
  __syncthreads();
  if (threadIdx.x < 64){
    int j = threadIdx.x;
    int p = chunk*64 + j;                 // 0..2047
    if (p < NP){
      float S = Ss[j]+Ss[j+1];
      float Q = Qs[j]+Qs[j+1];
      float mean = S*(1.0f/64.0f);
      float var  = (Q - S*mean)*(1.0f/63.0f);   // ddof=1
      x3[(b*3+0)*NP + p] = mean;
      x3[(b*3+1)*NP + p] = sqrtf(fmaxf(var,0.0f));
      x3[(b*3+2)*NP + p] = c1b[p];              // bias init (gemm atomically adds on top)
    }
    dmaxB[(size_t)b*KPAD + p] = (p < NPM) ? f2bf(fmaxf(Dm[j], Dm[j+1])) : (short)0;
  }
}

// ---------------- K_wB: conv1_w [NP][NPM] fp32 -> Wb [NP][KPAD] bf16 (zero-padded) ----------------
__global__ __launch_bounds__(256) void k_wB(const float* __restrict__ W, float* __restrict__ ws){
  short* Wb = (short*)(ws + OFF_WB);
  int o = blockIdx.y;
  int k = blockIdx.x*256 + threadIdx.x;
  Wb[(size_t)o*KPAD + k] = (k < NPM) ? f2bf(W[(size_t)o*NPM + k]) : (short)0;
}

// ---------------- K_wt: pack conv2 weights fp32 [(i*3+tap)][c]; conv3 weights bf16 [tap][c][i] ----------------
__global__ __launch_bounds__(256) void k_wt(const float* __restrict__ w2, const float* __restrict__ w3, float* __restrict__ ws){
  float* w2c = ws + OFF_W2C;
  short* w3b = (short*)(ws + OFF_W3B);
  int t = blockIdx.x*256 + threadIdx.x;
  if (t < C1*3*C2){
    int r = t / C2, c = t - r*C2;          // r = i*3+tap
    int i = r/3, tap = r - i*3;
    w2c[t] = w2[(c*C1+i)*3 + tap];
  }
  if (t < 3*C3*C2){
    int tap = t / (C3*C2);
    int r = t - tap*(C3*C2);
    int c = r / C2, i = r - c*C2;
    w3b[(tap*C3 + c)*C2 + i] = f2bf(w3[(c*C2+i)*3 + tap]);
  }
}

// ---------------- K2: d2[b,o] += sum_k dmax[b,k]*W[o,k] via MFMA bf16 ----------------
__global__ __launch_bounds__(256) void k_gemm(float* __restrict__ ws){
  const short* Ab = (const short*)(ws + OFF_DMAX); // [NB][KPAD]
  const short* Bb = (const short*)(ws + OFF_WB);   // [NP][KPAD]
  float* x3 = ws + OFF_X3;
  int wid  = __builtin_amdgcn_readfirstlane(threadIdx.x >> 6);
  int lane = threadIdx.x & 63;
  int ln = lane & 15, kq = lane >> 4;
  int n0  = blockIdx.x*32;                 // o tile pair base
  int m16 = (blockIdx.y*4 + wid)*16;       // b tile base (wave-uniform)
  int ks  = blockIdx.z*512;                // K split (16 steps of 32)
  f32x4 acc0 = {0.f,0.f,0.f,0.f}, acc1 = {0.f,0.f,0.f,0.f};
  int o0 = n0 + ln, o1 = n0 + 16 + ln;
  const short* ap  = Ab + (size_t)(m16 + ln)*KPAD + ks + kq*8;
  const short* bp0 = Bb + (size_t)min(o0, NP-1)*KPAD + ks + kq*8;
  const short* bp1 = Bb + (size_t)min(o1, NP-1)*KPAD + ks + kq*8;
  #pragma unroll 4
  for (int s=0; s<16; s++){
    short8 av = *(const short8*)(ap  + s*32);
    short8 b0 = *(const short8*)(bp0 + s*32);
    short8 b1 = *(const short8*)(bp1 + s*32);
    acc0 = __builtin_amdgcn_mfma_f32_16x16x32_bf16(av, b0, acc0, 0, 0, 0);
    acc1 = __builtin_amdgcn_mfma_f32_16x16x32_bf16(av, b1, acc1, 0, 0, 0);
  }
  // D[row=kq*4+r][col=ln]: row -> b offset, col -> o offset
  #pragma unroll
  for (int r=0;r<4;r++){
    int b = m16 + kq*4 + r;
    float* xp = x3 + ((size_t)b*3 + 2)*NP;
    if (o0 < NP) atomicAdd(xp + o0, acc0[r]);
    if (o1 < NP) atomicAdd(xp + o1, acc1[r]);
  }
}

// ---------------- K3: conv1f (3->32, k=5, pad=2) + fused BN1 stats + fused maxpool ----------------
// Thread = one l position, 32 channels sequential. Stats (sum/sumsq over UNPOOLED y1) via
// pair-sum (reusing the pooling shfl) + 5-level butterfly per channel -> LDS -> partials.
// Writes pooled RAW max h1raw[b][i][m] only (bn1 applied later in-place; pool/bn commute, a>0).
__global__ __launch_bounds__(256) void k_conv1f(const float* __restrict__ w1, const float* __restrict__ b1, float* __restrict__ ws){
  const float* x3 = ws + OFF_X3;
  float* h1 = ws + OFF_H1;      // pooled raw [b][i][m], m<LEN2
  float* ps = ws + OFF_PS;
  float* pq = ws + OFF_PQ;
  int b = blockIdx.y;
  int blk = blockIdx.x;
  int l = blk*256 + threadIdx.x;
  int lane = threadIdx.x & 63;
  int w = threadIdx.x >> 6;
  bool valid  = (l < LEN1);
  bool nvalid = ((l ^ 1) < LEN1);
  float xin[3][5];
  #pragma unroll
  for (int i=0;i<3;i++){
    #pragma unroll
    for (int j=0;j<5;j++){
      int t = l + j - 2;
      xin[i][j] = (valid && t >= 0 && t < LEN1) ? x3[(b*3+i)*NP + t] : 0.f;
    }
  }
  __shared__ float es[4][C1], eq[4][C1];
  int m = l >> 1;
  bool pstore = ((lane & 1) == 0) && (m < LEN2);
  #pragma unroll 8
  for (int c=0;c<C1;c++){
    float a = b1[c];
    #pragma unroll
    for (int i=0;i<3;i++){
      #pragma unroll
      for (int j=0;j<5;j++) a = fmaf(w1[(c*3+i)*5+j], xin[i][j], a);
    }
    float an = __shfl_xor(a, 1, 64);            // neighbor value (pool partner)
    if (pstore) h1[((size_t)b*C1 + c)*LEN2 + m] = fmaxf(a, an);
    float s0 = valid  ? a  : 0.f;
    float n0 = nvalid ? an : 0.f;
    float sp = s0 + n0;                          // pair-sum: level-1 of butterfly for free
    float qp = fmaf(s0, s0, n0*n0);
    sp += __shfl_xor(sp, 2,64); qp += __shfl_xor(qp, 2,64);
    sp += __shfl_xor(sp, 4,64); qp += __shfl_xor(qp, 4,64);
    sp += __shfl_xor(sp, 8,64); qp += __shfl_xor(qp, 8,64);
    sp += __shfl_xor(sp,16,64); qp += __shfl_xor(qp,16,64);
    sp += __shfl_xor(sp,32,64); qp += __shfl_xor(qp,32,64);
    if (lane == 0){ es[w][c] = sp; eq[w][c] = qp; }
  }
  __syncthreads();
  if (threadIdx.x < C1){
    int c = threadIdx.x;
    float S = es[0][c]+es[1][c]+es[2][c]+es[3][c];
    float Q = eq[0][c]+eq[1][c]+eq[2][c]+eq[3][c];
    ps[(size_t)c*NPART + b*8 + blk] = S;
    pq[(size_t)c*NPART + b*8 + blk] = Q;
  }
}

// ---------------- finalize BN from partials (+ optional out-zeroing for layer 3) ----------------
__global__ __launch_bounds__(256) void k_fin(const float* __restrict__ ps, const float* __restrict__ pq,
                                             const float* __restrict__ g, const float* __restrict__ be,
                                             float* __restrict__ stats, int C, int npart, double invN,
                                             float* __restrict__ outz){
  if (outz) outz[(size_t)threadIdx.x * C3 + blockIdx.x] = 0.f;  // layer-3: 128 blocks x 256 thr = NB*C3
  int c = blockIdx.x;
  double s=0.0, q=0.0;
  for (int j=threadIdx.x; j<npart; j+=256){ s += (double)ps[c*npart+j]; q += (double)pq[c*npart+j]; }
  #pragma unroll
  for (int off=32; off; off>>=1){ s += __shfl_xor(s,off,64); q += __shfl_xor(q,off,64); }
  __shared__ double rs[4], rq[4];
  int wid = threadIdx.x>>6, lane=threadIdx.x&63;
  if (lane==0){ rs[wid]=s; rq[wid]=q; }
  __syncthreads();
  if (threadIdx.x==0){
    double S = rs[0]+rs[1]+rs[2]+rs[3];
    double Q = rq[0]+rq[1]+rq[2]+rq[3];
    double mean = S*invN;
    double var  = Q*invN - mean*mean;
    double a = (double)g[c] / sqrt(var + 1e-5);
    stats[c]   = (float)a;
    stats[C+c] = (float)((double)be[c] - mean*a);
  }
}

// ---------------- K4: bn1 — in-place h1 = relu(a*h1raw + b), elementwise ----------------
__global__ __launch_bounds__(256) void k_bn1(float* __restrict__ ws){
  const float* st = ws + OFF_S1;
  float* h1 = ws + OFF_H1;
  int b = blockIdx.z, i = blockIdx.y;
  int m = blockIdx.x*256 + threadIdx.x;
  if (m < LEN2){
    float* p = h1 + ((size_t)b*C1 + i)*LEN2 + m;
    *p = fmaxf(fmaf(st[i], *p, st[C1+i]), 0.f);
  }
}

// ---------------- K5: conv2 (32->64) — lanes=channel; h via SMEM (grouped x2); weights via VMEM ----------------
__global__ __launch_bounds__(256) void k_conv2(const float* __restrict__ b2, float* __restrict__ ws){
  const float* h1  = ws + OFF_H1;     // [b][i][m], m<LEN2 (post-bn1)
  const float* w2c = ws + OFF_W2C;    // [(i*3+tap)][c]
  float* pmaxT = ws + OFF_PMAX;       // [b][m][c], m<LEN3
  float* ps = ws + OFF_PS;
  float* pq = ws + OFF_PQ;
  int b = blockIdx.y;
  int blk = blockIdx.x;               // 0..7 (128 positions each)
  int w  = __builtin_amdgcn_readfirstlane(threadIdx.x >> 6);
  int lane = threadIdx.x & 63;
  int p0 = blk*128 + w*32;            // wave-uniform
  int c  = lane;
#define AD2(p) float acc##p = b2[c];
  ACCS32(AD2)
  const float* hb = h1 + (size_t)b*C1*LEN2 + p0 - 1;
  const float* wb = w2c + c;
  #pragma unroll 1
  for (int i=0;i<C1;i+=2){
    const float* hpA = hb + (size_t)i*LEN2;      // wave-uniform -> s_load
    const float* hpB = hpA + LEN2;
    HS34(HLA)
    HS34(HLB)
    if (p0 == 0){ hh0 = 0.f; gg0 = 0.f; }
    if (p0 == 992){ hh32 = 0.f; hh33 = 0.f; gg32 = 0.f; gg33 = 0.f; }
    const float* wvA = wb + (i*3)*C2;            // per-lane coalesced VMEM
    const float* wvB = wb + ((i+1)*3)*C2;
    float w0a_ = wvA[0], w1a_ = wvA[C2], w2a_ = wvA[2*C2];
    float w0b_ = wvB[0], w1b_ = wvB[C2], w2b_ = wvB[2*C2];
    CONVSTEPS(CFA)
    CONVSTEPS(CFB)
  }
  int m0 = p0 >> 1;
  float* pp = pmaxT + ((size_t)b*LEN3 + m0)*C2 + c;
#define PST2(j,e,o) if (m0 + j < LEN3) pp[(size_t)(j)*C2] = fmaxf(acc##e, acc##o);
  POOL16(PST2)
  float ss = 0.f, qq = 0.f;
#define SAC2(p) if (p0 + p < LEN2){ ss += acc##p; qq = fmaf(acc##p, acc##p, qq); }
  ACCS32(SAC2)
  __shared__ float es[4][64], eq[4][64];
  es[w][lane] = ss; eq[w][lane] = qq;
  __syncthreads();
  if (w == 0){
    int pidx = b*8 + blk;
    float S = es[0][lane]+es[1][lane]+es[2][lane]+es[3][lane];
    float Q = eq[0][lane]+eq[1][lane]+eq[2][lane]+eq[3][lane];
    ps[lane*NPART + pidx] = S;
    pq[lane*NPART + pidx] = Q;
  }
}

// ---------------- K6: p2bf — h2T[b][m+1][c] = bf16(relu(bn2(pmaxT[b][m][c]))); zero pad rows ----------------
__global__ __launch_bounds__(256) void k_p2bf(float* __restrict__ ws){
  const float* pm = ws + OFF_PMAX;   // [b][m][c]
  const float* st = ws + OFF_S2;
  short* h2t = (short*)(ws + OFF_H2T); // [b][LPAD][C2], row r = position r-1
  int b = blockIdx.y;
  int idx = blockIdx.x*256 + threadIdx.x;
  if (idx < LEN3*C2){
    int m = idx >> 6, c = idx & 63;
    float v = fmaxf(fmaf(st[c], pm[((size_t)b*LEN3 + m)*C2 + c], st[C2+c]), 0.f);
    h2t[((size_t)b*LPAD + m + 1)*C2 + c] = f2bf(v);
  } else {
    int zr = idx - LEN3*C2;          // 192 pad slots: rows 0, 512, 513
    if (zr < 3*C2){
      int rsel = zr >> 6, c = zr & 63;
      int row = (rsel == 0) ? 0 : (511 + rsel);   // 0, 512, 513
      h2t[((size_t)b*LPAD + row)*C2 + c] = 0;
    }
  }
}

// ---------------- K7: conv3 via MFMA bf16, 4x4 register-blocked — STATS ONLY (no y3 store) ----------------
// y3 is never materialized: this pass computes BN3 partial sums; k_out3 recomputes conv3
// (≈1 µs of MFMA) and folds bn3+relu+mean, saving the 67MB y3t write + 67MB read.
__global__ __launch_bounds__(256) void k_conv3s(const float* __restrict__ b3, float* __restrict__ ws){
  const short* h2t = (const short*)(ws + OFF_H2T);  // [b][LPAD][C2]
  const short* w3b = (const short*)(ws + OFF_W3B);  // [tap][C3][C2]
  float* ps = ws + OFF_PS;
  float* pq = ws + OFF_PQ;
  int b   = blockIdx.y;
  int blk = blockIdx.x;                // 0..3 (128 positions)
  int wid = __builtin_amdgcn_readfirstlane(threadIdx.x >> 6);
  int lane = threadIdx.x & 63;
  int ln = lane & 15, kq = lane >> 4;
  int lh = wid & 1, ch = wid >> 1;     // wave-uniform
  int l0 = blk*128 + lh*64;            // l = l0 + lt*16 + ln
  int cbase = ch*64;                   // A-row c = cbase+ct*16+ln; D-row c = cbase+ct*16+kq*4+r
#define DECLB(ct) f32x4 bi##ct = *(const f32x4*)(b3 + cbase + ct*16 + kq*4);
  DECLB(0) DECLB(1) DECLB(2) DECLB(3)
#define DECLACC(lt,ct) f32x4 acc##lt##ct = bi##ct;
  TILES(DECLACC)
  const short* hB = h2t + ((size_t)b*LPAD + l0 + ln)*C2 + kq*8;  // + (lt*16 + t)*C2 + s*32
  const short* wA = w3b + (size_t)(cbase + ln)*C2 + kq*8;        // + (t*C3 + ct*16)*C2 + s*32
  #pragma unroll
  for (int t=0;t<3;t++){
    #pragma unroll
    for (int s=0;s<2;s++){
#define LDB(lt) short8 bv##lt = *(const short8*)(hB + (size_t)(lt*16 + t)*C2 + s*32);
      LDB(0) LDB(1) LDB(2) LDB(3)
#define LDA(ct) short8 av##ct = *(const short8*)(wA + (size_t)(t*C3 + ct*16)*C2 + s*32);
      LDA(0) LDA(1) LDA(2) LDA(3)
#define MM(lt,ct) acc##lt##ct = __builtin_amdgcn_mfma_f32_16x16x32_bf16(av##ct, bv##lt, acc##lt##ct, 0, 0, 0);
      TILES(MM)
#undef LDB
#undef LDA
    }
  }
  // fused stats: per (ct,r) sum over this wave's 64 l values
  int pidx = b*8 + blk*2 + lh;
  #pragma unroll
  for (int ct=0;ct<4;ct++){
    float s0=0.f,s1=0.f,s2=0.f,s3=0.f,q0=0.f,q1=0.f,q2=0.f,q3=0.f;
#define ACCST(lt,CT) if (CT == ct){ int l_ = l0 + lt*16 + ln; if (l_ < LEN3){ \
      s0 += acc##lt##CT[0]; q0 = fmaf(acc##lt##CT[0], acc##lt##CT[0], q0); \
      s1 += acc##lt##CT[1]; q1 = fmaf(acc##lt##CT[1], acc##lt##CT[1], q1); \
      s2 += acc##lt##CT[2]; q2 = fmaf(acc##lt##CT[2], acc##lt##CT[2], q2); \
      s3 += acc##lt##CT[3]; q3 = fmaf(acc##lt##CT[3], acc##lt##CT[3], q3); } }
    TILES(ACCST)
#undef ACCST
    RED4L(s0) RED4L(s1) RED4L(s2) RED4L(s3)
    RED4L(q0) RED4L(q1) RED4L(q2) RED4L(q3)
    if (ln == 0){
      int c0 = cbase + ct*16 + kq*4;
      ps[(size_t)(c0+0)*NPART + pidx] = s0;  pq[(size_t)(c0+0)*NPART + pidx] = q0;
      ps[(size_t)(c0+1)*NPART + pidx] = s1;  pq[(size_t)(c0+1)*NPART + pidx] = q1;
      ps[(size_t)(c0+2)*NPART + pidx] = s2;  pq[(size_t)(c0+2)*NPART + pidx] = q2;
      ps[(size_t)(c0+3)*NPART + pidx] = s3;  pq[(size_t)(c0+3)*NPART + pidx] = q3;
    }
  }
}

// ---------------- K9: conv3 recompute + bn3 + relu + mean -> out (atomic accumulate) ----------------
// Same MFMA tile loop as k_conv3s; out pre-zeroed by the layer-3 k_fin. 8 partials/(b,c).
__global__ __launch_bounds__(256) void k_out3(float* __restrict__ out, const float* __restrict__ b3,
                                              const float* __restrict__ ws){
  const short* h2t = (const short*)(ws + OFF_H2T);
  const short* w3b = (const short*)(ws + OFF_W3B);
  const float* st  = ws + OFF_S3;
  int b   = blockIdx.y;
  int blk = blockIdx.x;
  int wid = __builtin_amdgcn_readfirstlane(threadIdx.x >> 6);
  int lane = threadIdx.x & 63;
  int ln = lane & 15, kq = lane >> 4;
  int lh = wid & 1, ch = wid >> 1;
  int l0 = blk*128 + lh*64;
  int cbase = ch*64;
  DECLB(0) DECLB(1) DECLB(2) DECLB(3)
  TILES(DECLACC)
  const short* hB = h2t + ((size_t)b*LPAD + l0 + ln)*C2 + kq*8;
  const short* wA = w3b + (size_t)(cbase + ln)*C2 + kq*8;
  #pragma unroll
  for (int t=0;t<3;t++){
    #pragma unroll
    for (int s=0;s<2;s++){
#define LDB(lt) short8 bv##lt = *(const short8*)(hB + (size_t)(lt*16 + t)*C2 + s*32);
      LDB(0) LDB(1) LDB(2) LDB(3)
#define LDA(ct) short8 av##ct = *(const short8*)(wA + (size_t)(t*C3 + ct*16)*C2 + s*32);
      LDA(0) LDA(1) LDA(2) LDA(3)
      TILES(MM)
#undef LDB
#undef LDA
    }
  }
  // bn3 + relu + sum over l (this wave's slice), scaled by 1/511, atomically accumulated
  const float inv = 1.0f/511.0f;
  #pragma unroll
  for (int ct=0;ct<4;ct++){
    int c0 = cbase + ct*16 + kq*4;
    float a0 = st[c0+0], a1 = st[c0+1], a2 = st[c0+2], a3 = st[c0+3];
    float h0 = st[C3+c0+0], h1_ = st[C3+c0+1], h2_ = st[C3+c0+2], h3 = st[C3+c0+3];
    float s0=0.f,s1=0.f,s2=0.f,s3=0.f;
#define OSUM(lt,CT) if (CT == ct){ int l_ = l0 + lt*16 + ln; if (l_ < LEN3){ \
      s0 += fmaxf(fmaf(a0, acc##lt##CT[0], h0 ), 0.f); \
      s1 += fmaxf(fmaf(a1, acc##lt##CT[1], h1_), 0.f); \
      s2 += fmaxf(fmaf(a2, acc##lt##CT[2], h2_), 0.f); \
      s3 += fmaxf(fmaf(a3, acc##lt##CT[3], h3 ), 0.f); } }
    TILES(OSUM)
#undef OSUM
    RED4L(s0) RED4L(s1) RED4L(s2) RED4L(s3)
    if (ln == 0){
      atomicAdd(out + (size_t)b*C3 + c0+0, s0*inv);
      atomicAdd(out + (size_t)b*C3 + c0+1, s1*inv);
      atomicAdd(out + (size_t)b*C3 + c0+2, s2*inv);
      atomicAdd(out + (size_t)b*C3 + c0+3, s3*inv);
    }
  }
}

extern "C" void kernel_launch(void* const* d_in, const int* in_sizes, int n_in,
                              void* d_out, int out_size, void* d_ws, size_t ws_size,
                              hipStream_t stream) {
  const float* x   = (const float*)d_in[0];
  const float* c1w = (const float*)d_in[1];
  const float* c1b = (const float*)d_in[2];
  const float* w1  = (const float*)d_in[3];
  const float* b1  = (const float*)d_in[4];
  const float* g1  = (const float*)d_in[5];
  const float* be1 = (const float*)d_in[6];
  const float* w2  = (const float*)d_in[7];
  const float* b2  = (const float*)d_in[8];
  const float* g2  = (const float*)d_in[9];
  const float* be2 = (const float*)d_in[10];
  const float* w3  = (const float*)d_in[11];
  const float* b3  = (const float*)d_in[12];
  const float* g3  = (const float*)d_in[13];
  const float* be3 = (const float*)d_in[14];
  float* ws  = (float*)d_ws;
  float* out = (float*)d_out;

  hipLaunchKernelGGL(k_patch,  dim3(32,NB), dim3(256), 0, stream, x, c1b, ws);
  hipLaunchKernelGGL(k_wB,     dim3(KPAD/256, NP), dim3(256), 0, stream, c1w, ws);
  hipLaunchKernelGGL(k_wt,     dim3((3*C3*C2+255)/256), dim3(256), 0, stream, w2, w3, ws);
  hipLaunchKernelGGL(k_gemm,   dim3(64,4,4), dim3(256), 0, stream, ws);
  hipLaunchKernelGGL(k_conv1f, dim3(8,NB), dim3(256), 0, stream, w1, b1, ws);
  hipLaunchKernelGGL(k_fin,    dim3(C1), dim3(256), 0, stream, ws+OFF_PS, ws+OFF_PQ, g1, be1, ws+OFF_S1, C1, NPART, 1.0/((double)NB*LEN1), (float*)nullptr);
  hipLaunchKernelGGL(k_bn1,    dim3(4,C1,NB), dim3(256), 0, stream, ws);
  hipLaunchKernelGGL(k_conv2,  dim3(8,NB), dim3(256), 0, stream, b2, ws);
  hipLaunchKernelGGL(k_fin,    dim3(C2), dim3(256), 0, stream, ws+OFF_PS, ws+OFF_PQ, g2, be2, ws+OFF_S2, C2, NPART, 1.0/((double)NB*LEN2), (float*)nullptr);
  hipLaunchKernelGGL(k_p2bf,   dim3((LEN3*C2+3*C2+255)/256, NB), dim3(256), 0, stream, ws);
  hipLaunchKernelGGL(k_conv3s, dim3(4,NB), dim3(256), 0, stream, b3, ws);
  hipLaunchKernelGGL(k_fin,    dim3(C3), dim3(256), 0, stream, ws+OFF_PS, ws+OFF_PQ, g3, be3, ws+OFF_S3, C3, NPART, 1.0/((double)NB*LEN3), out);
  hipLaunchKernelGGL(k_out3,   dim3(4,NB), dim3(256), 0, stream, out, b3, ws);
}

// Round 4
// 332.103 us; speedup vs baseline: 1.0897x; 1.0897x over previous
//
#include <hip/hip_runtime.h>
#include <math.h>

#define NB 256
#define SEQ 65536
#define NP 2047
#define NPM 2046
#define KPAD 2048  // gemm K padded (bf16 operands zero-filled at k=2046,2047)
#define LEN1 2047
#define LEN2 1023
#define LEN3 511
#define C1 32
#define C2 64
#define C3 128
#define NPART 2048
#define NPART2 (NB*4)   // layer-2 partial count (dense stride — MUST match k_fin npart)
#define LPAD 514    // h2T rows: pos -1 .. 512 (zero-padded ends)
#define LPAD1 1026  // h1bf rows: pos -1 .. 1024 (rows 0,1024,1025 zeroed)

// workspace offsets (floats). Region timeline:
//   Y2: gemm Wb (bf16) -> h1rawT fp32 [b][m][i] (conv1f out) -> h2T bf16 (p2bf out)
//   Y1: h1bf bf16 [b][LPAD1][32] (bn1t out) ++ pmaxT fp32 [b][m][c] (conv2m out) — disjoint, both live
//   DMAX: dmax bf16 [b][KPAD]
#define OFF_X3   0
#define SZ_X3    (NB*3*NP)
#define OFF_DMAX (OFF_X3 + SZ_X3)
#define SZ_DMAX  (NB*NPM)
#define OFF_Y1   (OFF_DMAX + SZ_DMAX)
#define SZ_Y1    (NB*C1*LEN1)
#define OFF_Y2   (OFF_Y1 + SZ_Y1)
#define SZ_Y2    (NB*C2*LEN2)
#define OFF_S1   (OFF_Y2 + SZ_Y2)
#define OFF_S2   (OFF_S1 + 2*C1)
#define OFF_S3   (OFF_S2 + 2*C2)
#define OFF_W2C  (OFF_S3 + 2*C3)
#define OFF_W3B  (OFF_W2C + C1*C2*3)   // conv3 weights bf16 [tap][c][i]
#define OFF_PS   (OFF_W3B + C2*C3*3)
#define OFF_PQ   (OFF_PS + C3*NPART)
#define OFF_WB   OFF_Y2   // gemm W bf16 [NP][KPAD] (dead after gemm)
#define OFF_H1R  OFF_Y2   // pooled raw conv1 [b][m][i] fp32 (dead after bn1t)
#define OFF_H2T  OFF_Y2   // bf16 [b][LPAD][C2] (h1rawT dead after bn1t)
#define OFF_H1B  OFF_Y1                              // bf16 [b][LPAD1][C1]
#define OFF_PM   (OFF_Y1 + (NB*LPAD1*C1)/2)          // fp32 [b][m][c], m<LEN3
#define OFF_W2B  OFF_W2C  // conv2 weights bf16 [tap][c=64][i=32] (reuses old fp32 slot)

typedef __attribute__((ext_vector_type(8))) short short8;
typedef __attribute__((ext_vector_type(4))) float f32x4;

__device__ inline short f2bf(float f){
  union { float f; unsigned u; } x; x.f = f;
  unsigned r = x.u + 0x7FFF + ((x.u >> 16) & 1);   // RNE; inputs are normal finite
  return (short)(r >> 16);
}

#define RED4L(v) v += __shfl_xor(v,1,64); v += __shfl_xor(v,2,64); \
                 v += __shfl_xor(v,4,64); v += __shfl_xor(v,8,64);

// MFMA tile grid: (lt, ct) in 4x4
#define TILES(X) X(0,0) X(0,1) X(0,2) X(0,3) X(1,0) X(1,1) X(1,2) X(1,3) \
                 X(2,0) X(2,1) X(2,2) X(2,3) X(3,0) X(3,1) X(3,2) X(3,3)
#define DECLBIAS(P,ct) f32x4 bi##ct = *(const f32x4*)((P) + cbase + ct*16 + kq*4);
#define DECLACC(lt,ct) f32x4 acc##lt##ct = bi##ct;

// ---------------- K1: patch mean/std + dmax (bf16, [b][KPAD]) + x3-ch2 bias init ----------------
__global__ __launch_bounds__(256) void k_patch(const float* __restrict__ x, const float* __restrict__ c1b,
                                               float* __restrict__ ws){
  float* x3    = ws + OFF_X3;
  short* dmaxB = (short*)(ws + OFF_DMAX);   // bf16 [NB][KPAD], zero-padded k>=NPM
  int b = blockIdx.y;
  int chunk = blockIdx.x;              // 0..31, 2048 floats each
  const float* xr = x + (size_t)b*SEQ + chunk*2048;
  __shared__ float Ss[65], Qs[65], Dm[65];
  int w = threadIdx.x >> 6;
  int l = threadIdx.x & 63;
  #pragma unroll
  for (int i=0;i<2;i++){
    int seg = w*2 + i;
    int off = seg*256;
    float4 A = *(const float4*)(xr + off + l*4);
    float4 Bh = make_float4(0.f,0.f,0.f,0.f);
    if (l >= 56){
      int g = chunk*2048 + off + 256 + (l-56)*4;
      if (g + 3 < SEQ) Bh = *(const float4*)(xr + off + 256 + (l-56)*4);
    }
    int src = (l+8) & 63;
    float p0 = __shfl(A.x, src, 64), p1 = __shfl(A.y, src, 64),
          p2 = __shfl(A.z, src, 64), p3 = __shfl(A.w, src, 64);
    if (l >= 56){ p0=Bh.x; p1=Bh.y; p2=Bh.z; p3=Bh.w; }
    float s = (A.x+A.y)+(A.z+A.w);
    float q = fmaf(A.x,A.x, fmaf(A.y,A.y, fmaf(A.z,A.z, A.w*A.w)));
    float d = fmaxf(fmaxf(p0-A.x, p1-A.y), fmaxf(p2-A.z, p3-A.w));
    #pragma unroll
    for (int o=1;o<8;o<<=1){
      s += __shfl_xor(s,o,64);
      q += __shfl_xor(q,o,64);
      d  = fmaxf(d, __shfl_xor(d,o,64));
    }
    if ((l&7)==0){ int m = seg*8 + (l>>3); Ss[m]=s; Qs[m]=q; Dm[m]=d; }
  }
  if (w==0){
    float s=0.f,q=0.f,d=-1e30f;
    if (l < 8){
      int g = chunk*2048 + 2048 + l*4;
      if (g+3 < SEQ){
        float4 A = *(const float4*)(xr + 2048 + l*4);
        float4 P = make_float4(0.f,0.f,0.f,0.f);
        if (g+35 < SEQ) P = *(const float4*)(xr + 2048 + 32 + l*4);
        s = (A.x+A.y)+(A.z+A.w);
        q = fmaf(A.x,A.x, fmaf(A.y,A.y, fmaf(A.z,A.z, A.w*A.w)));
        d = fmaxf(fmaxf(P.x-A.x, P.y-A.y), fmaxf(P.z-A.z, P.w-A.w));
      }
    }
    #pragma unroll
    for (int o=1;o<8;o<<=1){
      s += __shfl_xor(s,o,64);
      q += __shfl_xor(q,o,64);
      d  = fmaxf(d, __shfl_xor(d,o,64));
    }
    if (l==0){ Ss[64]=s; Qs[64]=q; Dm[64]=d; }
  }
  __syncthreads();
  if (threadIdx.x < 64){
    int j = threadIdx.x;
    int p = chunk*64 + j;                 // 0..2047
    if (p < NP){
      float S = Ss[j]+Ss[j+1];
      float Q = Qs[j]+Qs[j+1];
      float mean = S*(1.0f/64.0f);
      float var  = (Q - S*mean)*(1.0f/63.0f);   // ddof=1
      x3[(b*3+0)*NP + p] = mean;
      x3[(b*3+1)*NP + p] = sqrtf(fmaxf(var,0.0f));
      x3[(b*3+2)*NP + p] = c1b[p];              // bias init (gemm atomically adds on top)
    }
    dmaxB[(size_t)b*KPAD + p] = (p < NPM) ? f2bf(fmaxf(Dm[j], Dm[j+1])) : (short)0;
  }
}

// ---------------- K_wB: conv1_w [NP][NPM] fp32 -> Wb [NP][KPAD] bf16 (zero-padded) ----------------
__global__ __launch_bounds__(256) void k_wB(const float* __restrict__ W, float* __restrict__ ws){
  short* Wb = (short*)(ws + OFF_WB);
  int o = blockIdx.y;
  int k = blockIdx.x*256 + threadIdx.x;
  Wb[(size_t)o*KPAD + k] = (k < NPM) ? f2bf(W[(size_t)o*NPM + k]) : (short)0;
}

// ---------------- K_wt: pack conv2 weights bf16 [tap][c][i]; conv3 weights bf16 [tap][c][i] ----------------
__global__ __launch_bounds__(256) void k_wt(const float* __restrict__ w2, const float* __restrict__ w3, float* __restrict__ ws){
  short* w2b = (short*)(ws + OFF_W2B);
  short* w3b = (short*)(ws + OFF_W3B);
  int t = blockIdx.x*256 + threadIdx.x;
  if (t < 3*C2*C1){                        // 6144
    int tap = t / (C2*C1);
    int r = t - tap*(C2*C1);
    int c = r >> 5, i = r & 31;
    w2b[t] = f2bf(w2[(c*C1 + i)*3 + tap]); // w2b[(tap*C2+c)*C1+i]
  }
  if (t < 3*C3*C2){
    int tap = t / (C3*C2);
    int r = t - tap*(C3*C2);
    int c = r / C2, i = r - c*C2;
    w3b[(tap*C3 + c)*C2 + i] = f2bf(w3[(c*C2+i)*3 + tap]);
  }
}

// ---------------- K2: d2[b,o] += sum_k dmax[b,k]*W[o,k] via MFMA bf16 ----------------
__global__ __launch_bounds__(256) void k_gemm(float* __restrict__ ws){
  const short* Ab = (const short*)(ws + OFF_DMAX); // [NB][KPAD]
  const short* Bb = (const short*)(ws + OFF_WB);   // [NP][KPAD]
  float* x3 = ws + OFF_X3;
  int wid  = __builtin_amdgcn_readfirstlane(threadIdx.x >> 6);
  int lane = threadIdx.x & 63;
  int ln = lane & 15, kq = lane >> 4;
  int n0  = blockIdx.x*32;                 // o tile pair base
  int m16 = (blockIdx.y*4 + wid)*16;       // b tile base (wave-uniform)
  int ks  = blockIdx.z*512;                // K split (16 steps of 32)
  f32x4 acc0 = {0.f,0.f,0.f,0.f}, acc1 = {0.f,0.f,0.f,0.f};
  int o0 = n0 + ln, o1 = n0 + 16 + ln;
  const short* ap  = Ab + (size_t)(m16 + ln)*KPAD + ks + kq*8;
  const short* bp0 = Bb + (size_t)min(o0, NP-1)*KPAD + ks + kq*8;
  const short* bp1 = Bb + (size_t)min(o1, NP-1)*KPAD + ks + kq*8;
  #pragma unroll 4
  for (int s=0; s<16; s++){
    short8 av = *(const short8*)(ap  + s*32);
    short8 b0 = *(const short8*)(bp0 + s*32);
    short8 b1 = *(const short8*)(bp1 + s*32);
    acc0 = __builtin_amdgcn_mfma_f32_16x16x32_bf16(av, b0, acc0, 0, 0, 0);
    acc1 = __builtin_amdgcn_mfma_f32_16x16x32_bf16(av, b1, acc1, 0, 0, 0);
  }
  // D[row=kq*4+r][col=ln]: row -> b offset, col -> o offset
  #pragma unroll
  for (int r=0;r<4;r++){
    int b = m16 + kq*4 + r;
    float* xp = x3 + ((size_t)b*3 + 2)*NP;
    if (o0 < NP) atomicAdd(xp + o0, acc0[r]);
    if (o1 < NP) atomicAdd(xp + o1, acc1[r]);
  }
}

// ---------------- K3: conv1f (3->32, k=5, pad=2) + fused BN1 stats + fused maxpool ----------------
// Thread = one l position, 32 channels (fully unrolled; pooled values buffered in regs).
// Writes pooled RAW max TRANSPOSED h1rawT[b][m][i] (contiguous 128B/thread, float4 stores).
__global__ __launch_bounds__(256) void k_conv1f(const float* __restrict__ w1, const float* __restrict__ b1, float* __restrict__ ws){
  const float* x3 = ws + OFF_X3;
  float* h1r = ws + OFF_H1R;    // pooled raw [b][m][i], m<LEN2
  float* ps = ws + OFF_PS;
  float* pq = ws + OFF_PQ;
  int b = blockIdx.y;
  int blk = blockIdx.x;
  int l = blk*256 + threadIdx.x;
  int lane = threadIdx.x & 63;
  int w = threadIdx.x >> 6;
  bool valid  = (l < LEN1);
  bool nvalid = ((l ^ 1) < LEN1);
  float xin[3][5];
  #pragma unroll
  for (int i=0;i<3;i++){
    #pragma unroll
    for (int j=0;j<5;j++){
      int t = l + j - 2;
      xin[i][j] = (valid && t >= 0 && t < LEN1) ? x3[(b*3+i)*NP + t] : 0.f;
    }
  }
  __shared__ float es[4][C1], eq[4][C1];
  int m = l >> 1;
  bool pstore = ((lane & 1) == 0) && (m < LEN2);
  float pv[C1];
  #pragma unroll
  for (int c=0;c<C1;c++){
    float a = b1[c];
    #pragma unroll
    for (int i=0;i<3;i++){
      #pragma unroll
      for (int j=0;j<5;j++) a = fmaf(w1[(c*3+i)*5+j], xin[i][j], a);
    }
    float an = __shfl_xor(a, 1, 64);            // neighbor value (pool partner)
    pv[c] = fmaxf(a, an);
    float s0 = valid  ? a  : 0.f;
    float n0 = nvalid ? an : 0.f;
    float sp = s0 + n0;                          // pair-sum: level-1 of butterfly for free
    float qp = fmaf(s0, s0, n0*n0);
    sp += __shfl_xor(sp, 2,64); qp += __shfl_xor(qp, 2,64);
    sp += __shfl_xor(sp, 4,64); qp += __shfl_xor(qp, 4,64);
    sp += __shfl_xor(sp, 8,64); qp += __shfl_xor(qp, 8,64);
    sp += __shfl_xor(sp,16,64); qp += __shfl_xor(qp,16,64);
    sp += __shfl_xor(sp,32,64); qp += __shfl_xor(qp,32,64);
    if (lane == 0){ es[w][c] = sp; eq[w][c] = qp; }
  }
  if (pstore){
    float* dst = h1r + ((size_t)b*LEN2 + m)*C1;
#define WR4(J) { f32x4 v_ = {pv[4*J], pv[4*J+1], pv[4*J+2], pv[4*J+3]}; *(f32x4*)(dst + 4*J) = v_; }
    WR4(0) WR4(1) WR4(2) WR4(3) WR4(4) WR4(5) WR4(6) WR4(7)
#undef WR4
  }
  __syncthreads();
  if (threadIdx.x < C1){
    int c = threadIdx.x;
    float S = es[0][c]+es[1][c]+es[2][c]+es[3][c];
    float Q = eq[0][c]+eq[1][c]+eq[2][c]+eq[3][c];
    ps[(size_t)c*NPART + b*8 + blk] = S;
    pq[(size_t)c*NPART + b*8 + blk] = Q;
  }
}

// ---------------- finalize BN from partials (+ optional out-zeroing for layer 3) ----------------
__global__ __launch_bounds__(256) void k_fin(const float* __restrict__ ps, const float* __restrict__ pq,
                                             const float* __restrict__ g, const float* __restrict__ be,
                                             float* __restrict__ stats, int C, int npart, double invN,
                                             float* __restrict__ outz){
  if (outz) outz[(size_t)threadIdx.x * C3 + blockIdx.x] = 0.f;  // layer-3: 128 blocks x 256 thr = NB*C3
  int c = blockIdx.x;
  double s=0.0, q=0.0;
  for (int j=threadIdx.x; j<npart; j+=256){ s += (double)ps[c*npart+j]; q += (double)pq[c*npart+j]; }
  #pragma unroll
  for (int off=32; off; off>>=1){ s += __shfl_xor(s,off,64); q += __shfl_xor(q,off,64); }
  __shared__ double rs[4], rq[4];
  int wid = threadIdx.x>>6, lane=threadIdx.x&63;
  if (lane==0){ rs[wid]=s; rq[wid]=q; }
  __syncthreads();
  if (threadIdx.x==0){
    double S = rs[0]+rs[1]+rs[2]+rs[3];
    double Q = rq[0]+rq[1]+rq[2]+rq[3];
    double mean = S*invN;
    double var  = Q*invN - mean*mean;
    double a = (double)g[c] / sqrt(var + 1e-5);
    stats[c]   = (float)a;
    stats[C+c] = (float)((double)be[c] - mean*a);
  }
}

// ---------------- K4: bn1t — h1bf[b][row][i] = bf16(relu(a*h1rawT[b][row-1][i]+b)); rows 0,1024,1025 zero ----------------
__global__ __launch_bounds__(256) void k_bn1t(float* __restrict__ ws){
  const float* st = ws + OFF_S1;
  const float* h1r = ws + OFF_H1R;
  short* h1b = (short*)(ws + OFF_H1B);   // [b][LPAD1][C1]
  int b = blockIdx.y;
  int idx8 = (blockIdx.x*256 + threadIdx.x)*8;
  if (idx8 >= LPAD1*C1) return;
  int row = idx8 >> 5, i0 = idx8 & 31;   // i0 in {0,8,16,24}
  short* dst = h1b + ((size_t)b*LPAD1 + row)*C1 + i0;
  short8 r;
  if (row == 0 || row >= 1024){
    r = (short8)0;
  } else {
    const float* src = h1r + ((size_t)b*LEN2 + (row-1))*C1 + i0;
    f32x4 vlo = *(const f32x4*)src, vhi = *(const f32x4*)(src+4);
    f32x4 alo = *(const f32x4*)(st + i0),      ahi = *(const f32x4*)(st + i0 + 4);
    f32x4 blo = *(const f32x4*)(st + C1 + i0), bhi = *(const f32x4*)(st + C1 + i0 + 4);
    #pragma unroll
    for (int j=0;j<4;j++){
      r[j]   = f2bf(fmaxf(fmaf(alo[j], vlo[j], blo[j]), 0.f));
      r[j+4] = f2bf(fmaxf(fmaf(ahi[j], vhi[j], bhi[j]), 0.f));
    }
  }
  *(short8*)dst = r;
}

// ---------------- K5: conv2m — MFMA bf16 (32->64, k=3, pad=1) + fused maxpool + fused BN2 stats ----------------
// Block = 4 waves, each wave: 64 positions (4 lt-tiles) x 64 out-channels (4 ct-tiles), K=32/tap.
// D: col(ln)=position, row(kq*4+r)=channel. Pool = adjacent-lane shfl max; store float4 [b][m][c].
__global__ __launch_bounds__(256) void k_conv2m(const float* __restrict__ b2, float* __restrict__ ws){
  const short* h1b = (const short*)(ws + OFF_H1B);  // [b][LPAD1][C1]
  const short* w2b = (const short*)(ws + OFF_W2B);  // [tap][C2][C1]
  float* pmaxT = ws + OFF_PM;                       // [b][m][c], m<LEN3
  float* ps = ws + OFF_PS;
  float* pq = ws + OFF_PQ;
  int b   = blockIdx.y;
  int blk = blockIdx.x;                // 0..3 (256 positions each)
  int w   = __builtin_amdgcn_readfirstlane(threadIdx.x >> 6);
  int lane = threadIdx.x & 63;
  int ln = lane & 15, kq = lane >> 4;
  int l0 = blk*256 + w*64;             // l = l0 + lt*16 + ln
  int cbase = 0;
  DECLBIAS(b2,0) DECLBIAS(b2,1) DECLBIAS(b2,2) DECLBIAS(b2,3)
  TILES(DECLACC)
  // preload 12 A fragments (tap x ct)
  const short* wA = w2b + (size_t)ln*C1 + kq*8;
#define LDW(T,ct) short8 aw##T##ct = *(const short8*)(wA + (size_t)(T*C2 + ct*16)*C1);
  LDW(0,0) LDW(0,1) LDW(0,2) LDW(0,3)
  LDW(1,0) LDW(1,1) LDW(1,2) LDW(1,3)
  LDW(2,0) LDW(2,1) LDW(2,2) LDW(2,3)
#undef LDW
  const short* hB = h1b + ((size_t)b*LPAD1 + l0 + ln)*C1 + kq*8;  // + (lt*16 + t)*C1
#define MMT0(lt,ct) acc##lt##ct = __builtin_amdgcn_mfma_f32_16x16x32_bf16(aw0##ct, bv##lt, acc##lt##ct, 0, 0, 0);
#define MMT1(lt,ct) acc##lt##ct = __builtin_amdgcn_mfma_f32_16x16x32_bf16(aw1##ct, bv##lt, acc##lt##ct, 0, 0, 0);
#define MMT2(lt,ct) acc##lt##ct = __builtin_amdgcn_mfma_f32_16x16x32_bf16(aw2##ct, bv##lt, acc##lt##ct, 0, 0, 0);
#define CSTEP(T) { \
    short8 bv0 = *(const short8*)(hB + (size_t)(0*16 + T)*C1); \
    short8 bv1 = *(const short8*)(hB + (size_t)(1*16 + T)*C1); \
    short8 bv2 = *(const short8*)(hB + (size_t)(2*16 + T)*C1); \
    short8 bv3 = *(const short8*)(hB + (size_t)(3*16 + T)*C1); \
    TILES(MMT##T) }
  CSTEP(0) CSTEP(1) CSTEP(2)
#undef CSTEP
  // pool (lane pairs along ln) + store float4 at [b][m][ct*16+kq*4]
#define PST(lt,ct) { \
    float p0_ = fmaxf(acc##lt##ct[0], __shfl_xor(acc##lt##ct[0],1,64)); \
    float p1_ = fmaxf(acc##lt##ct[1], __shfl_xor(acc##lt##ct[1],1,64)); \
    float p2_ = fmaxf(acc##lt##ct[2], __shfl_xor(acc##lt##ct[2],1,64)); \
    float p3_ = fmaxf(acc##lt##ct[3], __shfl_xor(acc##lt##ct[3],1,64)); \
    int l_ = l0 + lt*16 + ln; \
    if (!(ln & 1) && (l_ >> 1) < LEN3){ \
      f32x4 pv_ = {p0_, p1_, p2_, p3_}; \
      *(f32x4*)(pmaxT + ((size_t)b*LEN3 + (l_>>1))*C2 + ct*16 + kq*4) = pv_; } }
  TILES(PST)
#undef PST
  // fused stats over unpooled positions (mask l<LEN2)
  __shared__ float es[4][C2], eq[4][C2];
  #pragma unroll
  for (int ct=0;ct<4;ct++){
    float s0=0.f,s1=0.f,s2=0.f,s3=0.f,q0=0.f,q1=0.f,q2=0.f,q3=0.f;
#define ACCST(lt,CT) if (CT == ct){ int l_ = l0 + lt*16 + ln; if (l_ < LEN2){ \
      s0 += acc##lt##CT[0]; q0 = fmaf(acc##lt##CT[0], acc##lt##CT[0], q0); \
      s1 += acc##lt##CT[1]; q1 = fmaf(acc##lt##CT[1], acc##lt##CT[1], q1); \
      s2 += acc##lt##CT[2]; q2 = fmaf(acc##lt##CT[2], acc##lt##CT[2], q2); \
      s3 += acc##lt##CT[3]; q3 = fmaf(acc##lt##CT[3], acc##lt##CT[3], q3); } }
    TILES(ACCST)
#undef ACCST
    RED4L(s0) RED4L(s1) RED4L(s2) RED4L(s3)
    RED4L(q0) RED4L(q1) RED4L(q2) RED4L(q3)
    if (ln == 0){
      int c0 = ct*16 + kq*4;
      es[w][c0+0]=s0; es[w][c0+1]=s1; es[w][c0+2]=s2; es[w][c0+3]=s3;
      eq[w][c0+0]=q0; eq[w][c0+1]=q1; eq[w][c0+2]=q2; eq[w][c0+3]=q3;
    }
  }
  __syncthreads();
  if (threadIdx.x < C2){
    int c = threadIdx.x;
    float S = es[0][c]+es[1][c]+es[2][c]+es[3][c];
    float Q = eq[0][c]+eq[1][c]+eq[2][c]+eq[3][c];
    // DENSE layout, stride NPART2 — must match k_fin's npart (R3 fix: was NPART -> garbage BN2 stats)
    ps[(size_t)c*NPART2 + b*4 + blk] = S;
    pq[(size_t)c*NPART2 + b*4 + blk] = Q;
  }
}

// ---------------- K6: p2bf — h2T[b][m+1][c] = bf16(relu(bn2(pmaxT[b][m][c]))); zero pad rows ----------------
__global__ __launch_bounds__(256) void k_p2bf(float* __restrict__ ws){
  const float* pm = ws + OFF_PM;     // [b][m][c]
  const float* st = ws + OFF_S2;
  short* h2t = (short*)(ws + OFF_H2T); // [b][LPAD][C2], row r = position r-1
  int b = blockIdx.y;
  int idx = blockIdx.x*256 + threadIdx.x;
  if (idx < LEN3*C2){
    int m = idx >> 6, c = idx & 63;
    float v = fmaxf(fmaf(st[c], pm[((size_t)b*LEN3 + m)*C2 + c], st[C2+c]), 0.f);
    h2t[((size_t)b*LPAD + m + 1)*C2 + c] = f2bf(v);
  } else {
    int zr = idx - LEN3*C2;          // 192 pad slots: rows 0, 512, 513
    if (zr < 3*C2){
      int rsel = zr >> 6, c = zr & 63;
      int row = (rsel == 0) ? 0 : (511 + rsel);   // 0, 512, 513
      h2t[((size_t)b*LPAD + row)*C2 + c] = 0;
    }
  }
}

// ---------------- K7: conv3 via MFMA bf16, 4x4 register-blocked — STATS ONLY (no y3 store) ----------------
__global__ __launch_bounds__(256) void k_conv3s(const float* __restrict__ b3, float* __restrict__ ws){
  const short* h2t = (const short*)(ws + OFF_H2T);  // [b][LPAD][C2]
  const short* w3b = (const short*)(ws + OFF_W3B);  // [tap][C3][C2]
  float* ps = ws + OFF_PS;
  float* pq = ws + OFF_PQ;
  int b   = blockIdx.y;
  int blk = blockIdx.x;                // 0..3 (128 positions)
  int wid = __builtin_amdgcn_readfirstlane(threadIdx.x >> 6);
  int lane = threadIdx.x & 63;
  int ln = lane & 15, kq = lane >> 4;
  int lh = wid & 1, ch = wid >> 1;     // wave-uniform
  int l0 = blk*128 + lh*64;            // l = l0 + lt*16 + ln
  int cbase = ch*64;                   // A-row c = cbase+ct*16+ln; D-row c = cbase+ct*16+kq*4+r
  DECLBIAS(b3,0) DECLBIAS(b3,1) DECLBIAS(b3,2) DECLBIAS(b3,3)
  TILES(DECLACC)
  const short* hB = h2t + ((size_t)b*LPAD + l0 + ln)*C2 + kq*8;  // + (lt*16 + t)*C2 + s*32
  const short* wA = w3b + (size_t)(cbase + ln)*C2 + kq*8;        // + (t*C3 + ct*16)*C2 + s*32
  #pragma unroll
  for (int t=0;t<3;t++){
    #pragma unroll
    for (int s=0;s<2;s++){
#define LDB(lt) short8 bv##lt = *(const short8*)(hB + (size_t)(lt*16 + t)*C2 + s*32);
      LDB(0) LDB(1) LDB(2) LDB(3)
#define LDA(ct) short8 av##ct = *(const short8*)(wA + (size_t)(t*C3 + ct*16)*C2 + s*32);
      LDA(0) LDA(1) LDA(2) LDA(3)
#define MM(lt,ct) acc##lt##ct = __builtin_amdgcn_mfma_f32_16x16x32_bf16(av##ct, bv##lt, acc##lt##ct, 0, 0, 0);
      TILES(MM)
#undef LDB
#undef LDA
    }
  }
  // fused stats: per (ct,r) sum over this wave's 64 l values
  int pidx = b*8 + blk*2 + lh;
  #pragma unroll
  for (int ct=0;ct<4;ct++){
    float s0=0.f,s1=0.f,s2=0.f,s3=0.f,q0=0.f,q1=0.f,q2=0.f,q3=0.f;
#define ACCST(lt,CT) if (CT == ct){ int l_ = l0 + lt*16 + ln; if (l_ < LEN3){ \
      s0 += acc##lt##CT[0]; q0 = fmaf(acc##lt##CT[0], acc##lt##CT[0], q0); \
      s1 += acc##lt##CT[1]; q1 = fmaf(acc##lt##CT[1], acc##lt##CT[1], q1); \
      s2 += acc##lt##CT[2]; q2 = fmaf(acc##lt##CT[2], acc##lt##CT[2], q2); \
      s3 += acc##lt##CT[3]; q3 = fmaf(acc##lt##CT[3], acc##lt##CT[3], q3); } }
    TILES(ACCST)
#undef ACCST
    RED4L(s0) RED4L(s1) RED4L(s2) RED4L(s3)
    RED4L(q0) RED4L(q1) RED4L(q2) RED4L(q3)
    if (ln == 0){
      int c0 = cbase + ct*16 + kq*4;
      ps[(size_t)(c0+0)*NPART + pidx] = s0;  pq[(size_t)(c0+0)*NPART + pidx] = q0;
      ps[(size_t)(c0+1)*NPART + pidx] = s1;  pq[(size_t)(c0+1)*NPART + pidx] = q1;
      ps[(size_t)(c0+2)*NPART + pidx] = s2;  pq[(size_t)(c0+2)*NPART + pidx] = q2;
      ps[(size_t)(c0+3)*NPART + pidx] = s3;  pq[(size_t)(c0+3)*NPART + pidx] = q3;
    }
  }
}

// ---------------- K9: conv3 recompute + bn3 + relu + mean -> out (atomic accumulate) ----------------
__global__ __launch_bounds__(256) void k_out3(float* __restrict__ out, const float* __restrict__ b3,
                                              const float* __restrict__ ws){
  const short* h2t = (const short*)(ws + OFF_H2T);
  const short* w3b = (const short*)(ws + OFF_W3B);
  const float* st  = ws + OFF_S3;
  int b   = blockIdx.y;
  int blk = blockIdx.x;
  int wid = __builtin_amdgcn_readfirstlane(threadIdx.x >> 6);
  int lane = threadIdx.x & 63;
  int ln = lane & 15, kq = lane >> 4;
  int lh = wid & 1, ch = wid >> 1;
  int l0 = blk*128 + lh*64;
  int cbase = ch*64;
  DECLBIAS(b3,0) DECLBIAS(b3,1) DECLBIAS(b3,2) DECLBIAS(b3,3)
  TILES(DECLACC)
  const short* hB = h2t + ((size_t)b*LPAD + l0 + ln)*C2 + kq*8;
  const short* wA = w3b + (size_t)(cbase + ln)*C2 + kq*8;
  #pragma unroll
  for (int t=0;t<3;t++){
    #pragma unroll
    for (int s=0;s<2;s++){
#define LDB(lt) short8 bv##lt = *(const short8*)(hB + (size_t)(lt*16 + t)*C2 + s*32);
      LDB(0) LDB(1) LDB(2) LDB(3)
#define LDA(ct) short8 av##ct = *(const short8*)(wA + (size_t)(t*C3 + ct*16)*C2 + s*32);
      LDA(0) LDA(1) LDA(2) LDA(3)
      TILES(MM)
#undef LDB
#undef LDA
    }
  }
  // bn3 + relu + sum over l (this wave's slice), scaled by 1/511, atomically accumulated
  const float inv = 1.0f/511.0f;
  #pragma unroll
  for (int ct=0;ct<4;ct++){
    int c0 = cbase + ct*16 + kq*4;
    float a0 = st[c0+0], a1 = st[c0+1], a2 = st[c0+2], a3 = st[c0+3];
    float h0 = st[C3+c0+0], h1_ = st[C3+c0+1], h2_ = st[C3+c0+2], h3 = st[C3+c0+3];
    float s0=0.f,s1=0.f,s2=0.f,s3=0.f;
#define OSUM(lt,CT) if (CT == ct){ int l_ = l0 + lt*16 + ln; if (l_ < LEN3){ \
      s0 += fmaxf(fmaf(a0, acc##lt##CT[0], h0 ), 0.f); \
      s1 += fmaxf(fmaf(a1, acc##lt##CT[1], h1_), 0.f); \
      s2 += fmaxf(fmaf(a2, acc##lt##CT[2], h2_), 0.f); \
      s3 += fmaxf(fmaf(a3, acc##lt##CT[3], h3 ), 0.f); } }
    TILES(OSUM)
#undef OSUM
    RED4L(s0) RED4L(s1) RED4L(s2) RED4L(s3)
    if (ln == 0){
      atomicAdd(out + (size_t)b*C3 + c0+0, s0*inv);
      atomicAdd(out + (size_t)b*C3 + c0+1, s1*inv);
      atomicAdd(out + (size_t)b*C3 + c0+2, s2*inv);
      atomicAdd(out + (size_t)b*C3 + c0+3, s3*inv);
    }
  }
}

extern "C" void kernel_launch(void* const* d_in, const int* in_sizes, int n_in,
                              void* d_out, int out_size, void* d_ws, size_t ws_size,
                              hipStream_t stream) {
  const float* x   = (const float*)d_in[0];
  const float* c1w = (const float*)d_in[1];
  const float* c1b = (const float*)d_in[2];
  const float* w1  = (const float*)d_in[3];
  const float* b1  = (const float*)d_in[4];
  const float* g1  = (const float*)d_in[5];
  const float* be1 = (const float*)d_in[6];
  const float* w2  = (const float*)d_in[7];
  const float* b2  = (const float*)d_in[8];
  const float* g2  = (const float*)d_in[9];
  const float* be2 = (const float*)d_in[10];
  const float* w3  = (const float*)d_in[11];
  const float* b3  = (const float*)d_in[12];
  const float* g3  = (const float*)d_in[13];
  const float* be3 = (const float*)d_in[14];
  float* ws  = (float*)d_ws;
  float* out = (float*)d_out;

  hipLaunchKernelGGL(k_patch,  dim3(32,NB), dim3(256), 0, stream, x, c1b, ws);
  hipLaunchKernelGGL(k_wB,     dim3(KPAD/256, NP), dim3(256), 0, stream, c1w, ws);
  hipLaunchKernelGGL(k_wt,     dim3((3*C3*C2+255)/256), dim3(256), 0, stream, w2, w3, ws);
  hipLaunchKernelGGL(k_gemm,   dim3(64,4,4), dim3(256), 0, stream, ws);
  hipLaunchKernelGGL(k_conv1f, dim3(8,NB), dim3(256), 0, stream, w1, b1, ws);
  hipLaunchKernelGGL(k_fin,    dim3(C1), dim3(256), 0, stream, ws+OFF_PS, ws+OFF_PQ, g1, be1, ws+OFF_S1, C1, NPART, 1.0/((double)NB*LEN1), (float*)nullptr);
  hipLaunchKernelGGL(k_bn1t,   dim3((LPAD1*C1/8 + 255)/256, NB), dim3(256), 0, stream, ws);
  hipLaunchKernelGGL(k_conv2m, dim3(4,NB), dim3(256), 0, stream, b2, ws);
  hipLaunchKernelGGL(k_fin,    dim3(C2), dim3(256), 0, stream, ws+OFF_PS, ws+OFF_PQ, g2, be2, ws+OFF_S2, C2, NPART2, 1.0/((double)NB*LEN2), (float*)nullptr);
  hipLaunchKernelGGL(k_p2bf,   dim3((LEN3*C2+3*C2+255)/256, NB), dim3(256), 0, stream, ws);
  hipLaunchKernelGGL(k_conv3s, dim3(4,NB), dim3(256), 0, stream, b3, ws);
  hipLaunchKernelGGL(k_fin,    dim3(C3), dim3(256), 0, stream, ws+OFF_PS, ws+OFF_PQ, g3, be3, ws+OFF_S3, C3, NPART, 1.0/((double)NB*LEN3), out);
  hipLaunchKernelGGL(k_out3,   dim3(4,NB), dim3(256), 0, stream, out, b3, ws);
}

// Round 5
// 310.751 us; speedup vs baseline: 1.1646x; 1.0687x over previous
//
#include <hip/hip_runtime.h>
#include <math.h>

#define NB 256
#define SEQ 65536
#define NP 2047
#define NPM 2046
#define KPAD 2048  // gemm K padded (bf16 operands zero-filled at k=2046,2047)
#define LEN1 2047
#define LEN2 1023
#define LEN3 511
#define C1 32
#define C2 64
#define C3 128
#define NPART 2048
#define NPART2 (NB*4)   // layer-2 partial count (dense stride — MUST match k_fin npart)
#define LPAD 514    // h2T rows: pos -1 .. 512 (zero-padded ends)
#define LPAD1 1026  // h1bf rows: pos -1 .. 1024 (rows 0,1024,1025 zeroed)

// workspace offsets (floats). Region timeline:
//   Y2: gemm Wb (bf16) -> h1rawT fp32 [b][m][i] (conv1f out) -> h2T bf16 (p2bf out)
//   Y1: h1bf bf16 [b][LPAD1][32] (bn1t out) ++ pmaxT fp32 [b][m][c] (conv2m out) — disjoint, both live
//   DMAX: dmax bf16 [b][KPAD]
#define OFF_X3   0
#define SZ_X3    (NB*3*NP)
#define OFF_DMAX (OFF_X3 + SZ_X3)
#define SZ_DMAX  (NB*NPM)
#define OFF_Y1   (OFF_DMAX + SZ_DMAX)
#define SZ_Y1    (NB*C1*LEN1)
#define OFF_Y2   (OFF_Y1 + SZ_Y1)
#define SZ_Y2    (NB*C2*LEN2)
#define OFF_S1   (OFF_Y2 + SZ_Y2)
#define OFF_S2   (OFF_S1 + 2*C1)
#define OFF_S3   (OFF_S2 + 2*C2)
#define OFF_W2C  (OFF_S3 + 2*C3)
#define OFF_W3B  (OFF_W2C + C1*C2*3)   // conv3 weights bf16 [tap][c][i]
#define OFF_PS   (OFF_W3B + C2*C3*3)
#define OFF_PQ   (OFF_PS + C3*NPART)
#define OFF_WB   OFF_Y2   // gemm W bf16 [NP][KPAD] (dead after gemm)
#define OFF_H1R  OFF_Y2   // pooled raw conv1 [b][m][i] fp32 (dead after bn1t)
#define OFF_H2T  OFF_Y2   // bf16 [b][LPAD][C2] (h1rawT dead after bn1t)
#define OFF_H1B  OFF_Y1                              // bf16 [b][LPAD1][C1]
#define OFF_PM   (OFF_Y1 + (NB*LPAD1*C1)/2)          // fp32 [b][m][c], m<LEN3
#define OFF_W2B  OFF_W2C  // conv2 weights bf16 [tap][c=64][i=32] (reuses old fp32 slot)

typedef __attribute__((ext_vector_type(8))) short short8;
typedef __attribute__((ext_vector_type(4))) float f32x4;

__device__ inline short f2bf(float f){
  union { float f; unsigned u; } x; x.f = f;
  unsigned r = x.u + 0x7FFF + ((x.u >> 16) & 1);   // RNE; inputs are normal finite
  return (short)(r >> 16);
}

#define RED4L(v) v += __shfl_xor(v,1,64); v += __shfl_xor(v,2,64); \
                 v += __shfl_xor(v,4,64); v += __shfl_xor(v,8,64);

// MFMA tile grid: (lt, ct) in 4x4
#define TILES(X) X(0,0) X(0,1) X(0,2) X(0,3) X(1,0) X(1,1) X(1,2) X(1,3) \
                 X(2,0) X(2,1) X(2,2) X(2,3) X(3,0) X(3,1) X(3,2) X(3,3)
#define DECLBIAS(P,ct) f32x4 bi##ct = *(const f32x4*)((P) + cbase + ct*16 + kq*4);
#define DECLACC(lt,ct) f32x4 acc##lt##ct = bi##ct;

// ---------------- K1: patch mean/std + dmax (bf16, [b][KPAD]) + x3-ch2 bias init ----------------
__global__ __launch_bounds__(256) void k_patch(const float* __restrict__ x, const float* __restrict__ c1b,
                                               float* __restrict__ ws){
  float* x3    = ws + OFF_X3;
  short* dmaxB = (short*)(ws + OFF_DMAX);   // bf16 [NB][KPAD], zero-padded k>=NPM
  int b = blockIdx.y;
  int chunk = blockIdx.x;              // 0..31, 2048 floats each
  const float* xr = x + (size_t)b*SEQ + chunk*2048;
  __shared__ float Ss[65], Qs[65], Dm[65];
  int w = threadIdx.x >> 6;
  int l = threadIdx.x & 63;
  #pragma unroll
  for (int i=0;i<2;i++){
    int seg = w*2 + i;
    int off = seg*256;
    float4 A = *(const float4*)(xr + off + l*4);
    float4 Bh = make_float4(0.f,0.f,0.f,0.f);
    if (l >= 56){
      int g = chunk*2048 + off + 256 + (l-56)*4;
      if (g + 3 < SEQ) Bh = *(const float4*)(xr + off + 256 + (l-56)*4);
    }
    int src = (l+8) & 63;
    float p0 = __shfl(A.x, src, 64), p1 = __shfl(A.y, src, 64),
          p2 = __shfl(A.z, src, 64), p3 = __shfl(A.w, src, 64);
    if (l >= 56){ p0=Bh.x; p1=Bh.y; p2=Bh.z; p3=Bh.w; }
    float s = (A.x+A.y)+(A.z+A.w);
    float q = fmaf(A.x,A.x, fmaf(A.y,A.y, fmaf(A.z,A.z, A.w*A.w)));
    float d = fmaxf(fmaxf(p0-A.x, p1-A.y), fmaxf(p2-A.z, p3-A.w));
    #pragma unroll
    for (int o=1;o<8;o<<=1){
      s += __shfl_xor(s,o,64);
      q += __shfl_xor(q,o,64);
      d  = fmaxf(d, __shfl_xor(d,o,64));
    }
    if ((l&7)==0){ int m = seg*8 + (l>>3); Ss[m]=s; Qs[m]=q; Dm[m]=d; }
  }
  if (w==0){
    float s=0.f,q=0.f,d=-1e30f;
    if (l < 8){
      int g = chunk*2048 + 2048 + l*4;
      if (g+3 < SEQ){
        float4 A = *(const float4*)(xr + 2048 + l*4);
        float4 P = make_float4(0.f,0.f,0.f,0.f);
        if (g+35 < SEQ) P = *(const float4*)(xr + 2048 + 32 + l*4);
        s = (A.x+A.y)+(A.z+A.w);
        q = fmaf(A.x,A.x, fmaf(A.y,A.y, fmaf(A.z,A.z, A.w*A.w)));
        d = fmaxf(fmaxf(P.x-A.x, P.y-A.y), fmaxf(P.z-A.z, P.w-A.w));
      }
    }
    #pragma unroll
    for (int o=1;o<8;o<<=1){
      s += __shfl_xor(s,o,64);
      q += __shfl_xor(q,o,64);
      d  = fmaxf(d, __shfl_xor(d,o,64));
    }
    if (l==0){ Ss[64]=s; Qs[64]=q; Dm[64]=d; }
  }
  __syncthreads();
  if (threadIdx.x < 64){
    int j = threadIdx.x;
    int p = chunk*64 + j;                 // 0..2047
    if (p < NP){
      float S = Ss[j]+Ss[j+1];
      float Q = Qs[j]+Qs[j+1];
      float mean = S*(1.0f/64.0f);
      float var  = (Q - S*mean)*(1.0f/63.0f);   // ddof=1
      x3[(b*3+0)*NP + p] = mean;
      x3[(b*3+1)*NP + p] = sqrtf(fmaxf(var,0.0f));
      x3[(b*3+2)*NP + p] = c1b[p];              // bias init (gemm atomically adds on top)
    }
    dmaxB[(size_t)b*KPAD + p] = (p < NPM) ? f2bf(fmaxf(Dm[j], Dm[j+1])) : (short)0;
  }
}

// ---------------- K_wB: conv1_w [NP][NPM] fp32 -> Wb [NP][KPAD] bf16 (zero-padded) ----------------
__global__ __launch_bounds__(256) void k_wB(const float* __restrict__ W, float* __restrict__ ws){
  short* Wb = (short*)(ws + OFF_WB);
  int o = blockIdx.y;
  int k = blockIdx.x*256 + threadIdx.x;
  Wb[(size_t)o*KPAD + k] = (k < NPM) ? f2bf(W[(size_t)o*NPM + k]) : (short)0;
}

// ---------------- K_wt: pack conv2 weights bf16 [tap][c][i]; conv3 weights bf16 [tap][c][i] ----------------
__global__ __launch_bounds__(256) void k_wt(const float* __restrict__ w2, const float* __restrict__ w3, float* __restrict__ ws){
  short* w2b = (short*)(ws + OFF_W2B);
  short* w3b = (short*)(ws + OFF_W3B);
  int t = blockIdx.x*256 + threadIdx.x;
  if (t < 3*C2*C1){                        // 6144
    int tap = t / (C2*C1);
    int r = t - tap*(C2*C1);
    int c = r >> 5, i = r & 31;
    w2b[t] = f2bf(w2[(c*C1 + i)*3 + tap]); // w2b[(tap*C2+c)*C1+i]
  }
  if (t < 3*C3*C2){
    int tap = t / (C3*C2);
    int r = t - tap*(C3*C2);
    int c = r / C2, i = r - c*C2;
    w3b[(tap*C3 + c)*C2 + i] = f2bf(w3[(c*C2+i)*3 + tap]);
  }
}

// ---------------- K2: d2[b,o] += sum_k dmax[b,k]*W[o,k] via MFMA bf16 ----------------
__global__ __launch_bounds__(256) void k_gemm(float* __restrict__ ws){
  const short* Ab = (const short*)(ws + OFF_DMAX); // [NB][KPAD]
  const short* Bb = (const short*)(ws + OFF_WB);   // [NP][KPAD]
  float* x3 = ws + OFF_X3;
  int wid  = __builtin_amdgcn_readfirstlane(threadIdx.x >> 6);
  int lane = threadIdx.x & 63;
  int ln = lane & 15, kq = lane >> 4;
  int n0  = blockIdx.x*32;                 // o tile pair base
  int m16 = (blockIdx.y*4 + wid)*16;       // b tile base (wave-uniform)
  int ks  = blockIdx.z*512;                // K split (16 steps of 32)
  f32x4 acc0 = {0.f,0.f,0.f,0.f}, acc1 = {0.f,0.f,0.f,0.f};
  int o0 = n0 + ln, o1 = n0 + 16 + ln;
  const short* ap  = Ab + (size_t)(m16 + ln)*KPAD + ks + kq*8;
  const short* bp0 = Bb + (size_t)min(o0, NP-1)*KPAD + ks + kq*8;
  const short* bp1 = Bb + (size_t)min(o1, NP-1)*KPAD + ks + kq*8;
  #pragma unroll 4
  for (int s=0; s<16; s++){
    short8 av = *(const short8*)(ap  + s*32);
    short8 b0 = *(const short8*)(bp0 + s*32);
    short8 b1 = *(const short8*)(bp1 + s*32);
    acc0 = __builtin_amdgcn_mfma_f32_16x16x32_bf16(av, b0, acc0, 0, 0, 0);
    acc1 = __builtin_amdgcn_mfma_f32_16x16x32_bf16(av, b1, acc1, 0, 0, 0);
  }
  // D[row=kq*4+r][col=ln]: row -> b offset, col -> o offset
  #pragma unroll
  for (int r=0;r<4;r++){
    int b = m16 + kq*4 + r;
    float* xp = x3 + ((size_t)b*3 + 2)*NP;
    if (o0 < NP) atomicAdd(xp + o0, acc0[r]);
    if (o1 < NP) atomicAdd(xp + o1, acc1[r]);
  }
}

// ---------------- K3: conv1f v2 (3->32, k=5, pad=2) + fused BN1 stats + fused maxpool ----------------
// Lane = output channel (c = lane&31); half-wave (h = lane>>5) = 32-position block held in registers.
// R4 profile showed v1 latency-bound on 352 serial ds_bpermute shuffles/thread (VALUBusy 28%).
// v2: stats in-register (no shuffles), pool between registers, ONE shfl_xor(32) at the end.
// x3 reads are half-wave-uniform broadcasts (L1-resident ~3KB/block). Stores [b][m][c] dword-coalesced.
__global__ __launch_bounds__(256) void k_conv1f(const float* __restrict__ w1, const float* __restrict__ b1, float* __restrict__ ws){
  const float* x3 = ws + OFF_X3;
  float* h1r = ws + OFF_H1R;    // pooled raw [b][m][c], m<LEN2
  float* ps = ws + OFF_PS;
  float* pq = ws + OFF_PQ;
  int b = blockIdx.y;
  int blk = blockIdx.x;                 // 0..7 (256 positions per block)
  int w = threadIdx.x >> 6;             // wave 0..3 (64 positions)
  int lane = threadIdx.x & 63;
  int h = lane >> 5, c = lane & 31;     // half-wave position block, channel
  int p0 = blk*256 + w*64 + h*32;       // this lane's 32 positions: p0..p0+31
  // per-lane weights (15) + bias
  float wv[3][5];
  #pragma unroll
  for (int i=0;i<3;i++){
    #pragma unroll
    for (int j=0;j<5;j++) wv[i][j] = w1[(c*3+i)*5+j];
  }
  float bc = b1[c];
  const float* xb = x3 + (size_t)b*3*NP;
  float s = 0.f, q = 0.f;
  #pragma unroll
  for (int k0=0;k0<32;k0+=8){
    // x window for positions p0+k0 .. p0+k0+7, taps -2..+2 => g in [p0+k0-2, p0+k0+9]
    float xv[3][12];
    #pragma unroll
    for (int i=0;i<3;i++){
      #pragma unroll
      for (int t=0;t<12;t++){
        int g = p0 + k0 - 2 + t;
        xv[i][t] = (g >= 0 && g < LEN1) ? xb[(size_t)i*NP + g] : 0.f;
      }
    }
    float acc[8];
    #pragma unroll
    for (int k=0;k<8;k++){
      float a = bc;
      #pragma unroll
      for (int i=0;i<3;i++){
        #pragma unroll
        for (int j=0;j<5;j++) a = fmaf(wv[i][j], xv[i][k+j], a);
      }
      acc[k] = a;
      if (p0 + k0 + k < LEN1){ s += a; q = fmaf(a, a, q); }   // stats over UNPOOLED y1
    }
    // pool pairs (2t, 2t+1) -> m ; store [b][m][c] (coalesced dword across 32 lanes)
    #pragma unroll
    for (int t=0;t<4;t++){
      int m = ((p0 + k0) >> 1) + t;
      if (m < LEN2) h1r[((size_t)b*LEN2 + m)*C1 + c] = fmaxf(acc[2*t], acc[2*t+1]);
    }
  }
  // combine the two half-wave position blocks, then waves via LDS
  s += __shfl_xor(s, 32, 64);
  q += __shfl_xor(q, 32, 64);
  __shared__ float es[4][C1], eq[4][C1];
  if (h == 0){ es[w][c] = s; eq[w][c] = q; }
  __syncthreads();
  if (threadIdx.x < C1){
    int cc = threadIdx.x;
    float S = es[0][cc]+es[1][cc]+es[2][cc]+es[3][cc];
    float Q = eq[0][cc]+eq[1][cc]+eq[2][cc]+eq[3][cc];
    ps[(size_t)cc*NPART + b*8 + blk] = S;
    pq[(size_t)cc*NPART + b*8 + blk] = Q;
  }
}

// ---------------- finalize BN from partials (+ optional out-zeroing for layer 3) ----------------
__global__ __launch_bounds__(256) void k_fin(const float* __restrict__ ps, const float* __restrict__ pq,
                                             const float* __restrict__ g, const float* __restrict__ be,
                                             float* __restrict__ stats, int C, int npart, double invN,
                                             float* __restrict__ outz){
  if (outz) outz[(size_t)threadIdx.x * C3 + blockIdx.x] = 0.f;  // layer-3: 128 blocks x 256 thr = NB*C3
  int c = blockIdx.x;
  double s=0.0, q=0.0;
  for (int j=threadIdx.x; j<npart; j+=256){ s += (double)ps[c*npart+j]; q += (double)pq[c*npart+j]; }
  #pragma unroll
  for (int off=32; off; off>>=1){ s += __shfl_xor(s,off,64); q += __shfl_xor(q,off,64); }
  __shared__ double rs[4], rq[4];
  int wid = threadIdx.x>>6, lane=threadIdx.x&63;
  if (lane==0){ rs[wid]=s; rq[wid]=q; }
  __syncthreads();
  if (threadIdx.x==0){
    double S = rs[0]+rs[1]+rs[2]+rs[3];
    double Q = rq[0]+rq[1]+rq[2]+rq[3];
    double mean = S*invN;
    double var  = Q*invN - mean*mean;
    double a = (double)g[c] / sqrt(var + 1e-5);
    stats[c]   = (float)a;
    stats[C+c] = (float)((double)be[c] - mean*a);
  }
}

// ---------------- K4: bn1t — h1bf[b][row][i] = bf16(relu(a*h1rawT[b][row-1][i]+b)); rows 0,1024,1025 zero ----------------
__global__ __launch_bounds__(256) void k_bn1t(float* __restrict__ ws){
  const float* st = ws + OFF_S1;
  const float* h1r = ws + OFF_H1R;
  short* h1b = (short*)(ws + OFF_H1B);   // [b][LPAD1][C1]
  int b = blockIdx.y;
  int idx8 = (blockIdx.x*256 + threadIdx.x)*8;
  if (idx8 >= LPAD1*C1) return;
  int row = idx8 >> 5, i0 = idx8 & 31;   // i0 in {0,8,16,24}
  short* dst = h1b + ((size_t)b*LPAD1 + row)*C1 + i0;
  short8 r;
  if (row == 0 || row >= 1024){
    r = (short8)0;
  } else {
    const float* src = h1r + ((size_t)b*LEN2 + (row-1))*C1 + i0;
    f32x4 vlo = *(const f32x4*)src, vhi = *(const f32x4*)(src+4);
    f32x4 alo = *(const f32x4*)(st + i0),      ahi = *(const f32x4*)(st + i0 + 4);
    f32x4 blo = *(const f32x4*)(st + C1 + i0), bhi = *(const f32x4*)(st + C1 + i0 + 4);
    #pragma unroll
    for (int j=0;j<4;j++){
      r[j]   = f2bf(fmaxf(fmaf(alo[j], vlo[j], blo[j]), 0.f));
      r[j+4] = f2bf(fmaxf(fmaf(ahi[j], vhi[j], bhi[j]), 0.f));
    }
  }
  *(short8*)dst = r;
}

// ---------------- K5: conv2m — MFMA bf16 (32->64, k=3, pad=1) + fused maxpool + fused BN2 stats ----------------
// Block = 4 waves, each wave: 64 positions (4 lt-tiles) x 64 out-channels (4 ct-tiles), K=32/tap.
// D: col(ln)=position, row(kq*4+r)=channel. Pool = adjacent-lane shfl max; store float4 [b][m][c].
__global__ __launch_bounds__(256) void k_conv2m(const float* __restrict__ b2, float* __restrict__ ws){
  const short* h1b = (const short*)(ws + OFF_H1B);  // [b][LPAD1][C1]
  const short* w2b = (const short*)(ws + OFF_W2B);  // [tap][C2][C1]
  float* pmaxT = ws + OFF_PM;                       // [b][m][c], m<LEN3
  float* ps = ws + OFF_PS;
  float* pq = ws + OFF_PQ;
  int b   = blockIdx.y;
  int blk = blockIdx.x;                // 0..3 (256 positions each)
  int w   = __builtin_amdgcn_readfirstlane(threadIdx.x >> 6);
  int lane = threadIdx.x & 63;
  int ln = lane & 15, kq = lane >> 4;
  int l0 = blk*256 + w*64;             // l = l0 + lt*16 + ln
  int cbase = 0;
  DECLBIAS(b2,0) DECLBIAS(b2,1) DECLBIAS(b2,2) DECLBIAS(b2,3)
  TILES(DECLACC)
  // preload 12 A fragments (tap x ct)
  const short* wA = w2b + (size_t)ln*C1 + kq*8;
#define LDW(T,ct) short8 aw##T##ct = *(const short8*)(wA + (size_t)(T*C2 + ct*16)*C1);
  LDW(0,0) LDW(0,1) LDW(0,2) LDW(0,3)
  LDW(1,0) LDW(1,1) LDW(1,2) LDW(1,3)
  LDW(2,0) LDW(2,1) LDW(2,2) LDW(2,3)
#undef LDW
  const short* hB = h1b + ((size_t)b*LPAD1 + l0 + ln)*C1 + kq*8;  // + (lt*16 + t)*C1
#define MMT0(lt,ct) acc##lt##ct = __builtin_amdgcn_mfma_f32_16x16x32_bf16(aw0##ct, bv##lt, acc##lt##ct, 0, 0, 0);
#define MMT1(lt,ct) acc##lt##ct = __builtin_amdgcn_mfma_f32_16x16x32_bf16(aw1##ct, bv##lt, acc##lt##ct, 0, 0, 0);
#define MMT2(lt,ct) acc##lt##ct = __builtin_amdgcn_mfma_f32_16x16x32_bf16(aw2##ct, bv##lt, acc##lt##ct, 0, 0, 0);
#define CSTEP(T) { \
    short8 bv0 = *(const short8*)(hB + (size_t)(0*16 + T)*C1); \
    short8 bv1 = *(const short8*)(hB + (size_t)(1*16 + T)*C1); \
    short8 bv2 = *(const short8*)(hB + (size_t)(2*16 + T)*C1); \
    short8 bv3 = *(const short8*)(hB + (size_t)(3*16 + T)*C1); \
    TILES(MMT##T) }
  CSTEP(0) CSTEP(1) CSTEP(2)
#undef CSTEP
  // pool (lane pairs along ln) + store float4 at [b][m][ct*16+kq*4]
#define PST(lt,ct) { \
    float p0_ = fmaxf(acc##lt##ct[0], __shfl_xor(acc##lt##ct[0],1,64)); \
    float p1_ = fmaxf(acc##lt##ct[1], __shfl_xor(acc##lt##ct[1],1,64)); \
    float p2_ = fmaxf(acc##lt##ct[2], __shfl_xor(acc##lt##ct[2],1,64)); \
    float p3_ = fmaxf(acc##lt##ct[3], __shfl_xor(acc##lt##ct[3],1,64)); \
    int l_ = l0 + lt*16 + ln; \
    if (!(ln & 1) && (l_ >> 1) < LEN3){ \
      f32x4 pv_ = {p0_, p1_, p2_, p3_}; \
      *(f32x4*)(pmaxT + ((size_t)b*LEN3 + (l_>>1))*C2 + ct*16 + kq*4) = pv_; } }
  TILES(PST)
#undef PST
  // fused stats over unpooled positions (mask l<LEN2)
  __shared__ float es[4][C2], eq[4][C2];
  #pragma unroll
  for (int ct=0;ct<4;ct++){
    float s0=0.f,s1=0.f,s2=0.f,s3=0.f,q0=0.f,q1=0.f,q2=0.f,q3=0.f;
#define ACCST(lt,CT) if (CT == ct){ int l_ = l0 + lt*16 + ln; if (l_ < LEN2){ \
      s0 += acc##lt##CT[0]; q0 = fmaf(acc##lt##CT[0], acc##lt##CT[0], q0); \
      s1 += acc##lt##CT[1]; q1 = fmaf(acc##lt##CT[1], acc##lt##CT[1], q1); \
      s2 += acc##lt##CT[2]; q2 = fmaf(acc##lt##CT[2], acc##lt##CT[2], q2); \
      s3 += acc##lt##CT[3]; q3 = fmaf(acc##lt##CT[3], acc##lt##CT[3], q3); } }
    TILES(ACCST)
#undef ACCST
    RED4L(s0) RED4L(s1) RED4L(s2) RED4L(s3)
    RED4L(q0) RED4L(q1) RED4L(q2) RED4L(q3)
    if (ln == 0){
      int c0 = ct*16 + kq*4;
      es[w][c0+0]=s0; es[w][c0+1]=s1; es[w][c0+2]=s2; es[w][c0+3]=s3;
      eq[w][c0+0]=q0; eq[w][c0+1]=q1; eq[w][c0+2]=q2; eq[w][c0+3]=q3;
    }
  }
  __syncthreads();
  if (threadIdx.x < C2){
    int c = threadIdx.x;
    float S = es[0][c]+es[1][c]+es[2][c]+es[3][c];
    float Q = eq[0][c]+eq[1][c]+eq[2][c]+eq[3][c];
    // DENSE layout, stride NPART2 — must match k_fin's npart (R3 fix: was NPART -> garbage BN2 stats)
    ps[(size_t)c*NPART2 + b*4 + blk] = S;
    pq[(size_t)c*NPART2 + b*4 + blk] = Q;
  }
}

// ---------------- K6: p2bf — h2T[b][m+1][c] = bf16(relu(bn2(pmaxT[b][m][c]))); zero pad rows ----------------
__global__ __launch_bounds__(256) void k_p2bf(float* __restrict__ ws){
  const float* pm = ws + OFF_PM;     // [b][m][c]
  const float* st = ws + OFF_S2;
  short* h2t = (short*)(ws + OFF_H2T); // [b][LPAD][C2], row r = position r-1
  int b = blockIdx.y;
  int idx = blockIdx.x*256 + threadIdx.x;
  if (idx < LEN3*C2){
    int m = idx >> 6, c = idx & 63;
    float v = fmaxf(fmaf(st[c], pm[((size_t)b*LEN3 + m)*C2 + c], st[C2+c]), 0.f);
    h2t[((size_t)b*LPAD + m + 1)*C2 + c] = f2bf(v);
  } else {
    int zr = idx - LEN3*C2;          // 192 pad slots: rows 0, 512, 513
    if (zr < 3*C2){
      int rsel = zr >> 6, c = zr & 63;
      int row = (rsel == 0) ? 0 : (511 + rsel);   // 0, 512, 513
      h2t[((size_t)b*LPAD + row)*C2 + c] = 0;
    }
  }
}

// ---------------- K7: conv3 via MFMA bf16, 4x4 register-blocked — STATS ONLY (no y3 store) ----------------
__global__ __launch_bounds__(256) void k_conv3s(const float* __restrict__ b3, float* __restrict__ ws){
  const short* h2t = (const short*)(ws + OFF_H2T);  // [b][LPAD][C2]
  const short* w3b = (const short*)(ws + OFF_W3B);  // [tap][C3][C2]
  float* ps = ws + OFF_PS;
  float* pq = ws + OFF_PQ;
  int b   = blockIdx.y;
  int blk = blockIdx.x;                // 0..3 (128 positions)
  int wid = __builtin_amdgcn_readfirstlane(threadIdx.x >> 6);
  int lane = threadIdx.x & 63;
  int ln = lane & 15, kq = lane >> 4;
  int lh = wid & 1, ch = wid >> 1;     // wave-uniform
  int l0 = blk*128 + lh*64;            // l = l0 + lt*16 + ln
  int cbase = ch*64;                   // A-row c = cbase+ct*16+ln; D-row c = cbase+ct*16+kq*4+r
  DECLBIAS(b3,0) DECLBIAS(b3,1) DECLBIAS(b3,2) DECLBIAS(b3,3)
  TILES(DECLACC)
  const short* hB = h2t + ((size_t)b*LPAD + l0 + ln)*C2 + kq*8;  // + (lt*16 + t)*C2 + s*32
  const short* wA = w3b + (size_t)(cbase + ln)*C2 + kq*8;        // + (t*C3 + ct*16)*C2 + s*32
  #pragma unroll
  for (int t=0;t<3;t++){
    #pragma unroll
    for (int s=0;s<2;s++){
#define LDB(lt) short8 bv##lt = *(const short8*)(hB + (size_t)(lt*16 + t)*C2 + s*32);
      LDB(0) LDB(1) LDB(2) LDB(3)
#define LDA(ct) short8 av##ct = *(const short8*)(wA + (size_t)(t*C3 + ct*16)*C2 + s*32);
      LDA(0) LDA(1) LDA(2) LDA(3)
#define MM(lt,ct) acc##lt##ct = __builtin_amdgcn_mfma_f32_16x16x32_bf16(av##ct, bv##lt, acc##lt##ct, 0, 0, 0);
      TILES(MM)
#undef LDB
#undef LDA
    }
  }
  // fused stats: per (ct,r) sum over this wave's 64 l values
  int pidx = b*8 + blk*2 + lh;
  #pragma unroll
  for (int ct=0;ct<4;ct++){
    float s0=0.f,s1=0.f,s2=0.f,s3=0.f,q0=0.f,q1=0.f,q2=0.f,q3=0.f;
#define ACCST(lt,CT) if (CT == ct){ int l_ = l0 + lt*16 + ln; if (l_ < LEN3){ \
      s0 += acc##lt##CT[0]; q0 = fmaf(acc##lt##CT[0], acc##lt##CT[0], q0); \
      s1 += acc##lt##CT[1]; q1 = fmaf(acc##lt##CT[1], acc##lt##CT[1], q1); \
      s2 += acc##lt##CT[2]; q2 = fmaf(acc##lt##CT[2], acc##lt##CT[2], q2); \
      s3 += acc##lt##CT[3]; q3 = fmaf(acc##lt##CT[3], acc##lt##CT[3], q3); } }
    TILES(ACCST)
#undef ACCST
    RED4L(s0) RED4L(s1) RED4L(s2) RED4L(s3)
    RED4L(q0) RED4L(q1) RED4L(q2) RED4L(q3)
    if (ln == 0){
      int c0 = cbase + ct*16 + kq*4;
      ps[(size_t)(c0+0)*NPART + pidx] = s0;  pq[(size_t)(c0+0)*NPART + pidx] = q0;
      ps[(size_t)(c0+1)*NPART + pidx] = s1;  pq[(size_t)(c0+1)*NPART + pidx] = q1;
      ps[(size_t)(c0+2)*NPART + pidx] = s2;  pq[(size_t)(c0+2)*NPART + pidx] = q2;
      ps[(size_t)(c0+3)*NPART + pidx] = s3;  pq[(size_t)(c0+3)*NPART + pidx] = q3;
    }
  }
}

// ---------------- K9: conv3 recompute + bn3 + relu + mean -> out (atomic accumulate) ----------------
__global__ __launch_bounds__(256) void k_out3(float* __restrict__ out, const float* __restrict__ b3,
                                              const float* __restrict__ ws){
  const short* h2t = (const short*)(ws + OFF_H2T);
  const short* w3b = (const short*)(ws + OFF_W3B);
  const float* st  = ws + OFF_S3;
  int b   = blockIdx.y;
  int blk = blockIdx.x;
  int wid = __builtin_amdgcn_readfirstlane(threadIdx.x >> 6);
  int lane = threadIdx.x & 63;
  int ln = lane & 15, kq = lane >> 4;
  int lh = wid & 1, ch = wid >> 1;
  int l0 = blk*128 + lh*64;
  int cbase = ch*64;
  DECLBIAS(b3,0) DECLBIAS(b3,1) DECLBIAS(b3,2) DECLBIAS(b3,3)
  TILES(DECLACC)
  const short* hB = h2t + ((size_t)b*LPAD + l0 + ln)*C2 + kq*8;
  const short* wA = w3b + (size_t)(cbase + ln)*C2 + kq*8;
  #pragma unroll
  for (int t=0;t<3;t++){
    #pragma unroll
    for (int s=0;s<2;s++){
#define LDB(lt) short8 bv##lt = *(const short8*)(hB + (size_t)(lt*16 + t)*C2 + s*32);
      LDB(0) LDB(1) LDB(2) LDB(3)
#define LDA(ct) short8 av##ct = *(const short8*)(wA + (size_t)(t*C3 + ct*16)*C2 + s*32);
      LDA(0) LDA(1) LDA(2) LDA(3)
      TILES(MM)
#undef LDB
#undef LDA
    }
  }
  // bn3 + relu + sum over l (this wave's slice), scaled by 1/511, atomically accumulated
  const float inv = 1.0f/511.0f;
  #pragma unroll
  for (int ct=0;ct<4;ct++){
    int c0 = cbase + ct*16 + kq*4;
    float a0 = st[c0+0], a1 = st[c0+1], a2 = st[c0+2], a3 = st[c0+3];
    float h0 = st[C3+c0+0], h1_ = st[C3+c0+1], h2_ = st[C3+c0+2], h3 = st[C3+c0+3];
    float s0=0.f,s1=0.f,s2=0.f,s3=0.f;
#define OSUM(lt,CT) if (CT == ct){ int l_ = l0 + lt*16 + ln; if (l_ < LEN3){ \
      s0 += fmaxf(fmaf(a0, acc##lt##CT[0], h0 ), 0.f); \
      s1 += fmaxf(fmaf(a1, acc##lt##CT[1], h1_), 0.f); \
      s2 += fmaxf(fmaf(a2, acc##lt##CT[2], h2_), 0.f); \
      s3 += fmaxf(fmaf(a3, acc##lt##CT[3], h3 ), 0.f); } }
    TILES(OSUM)
#undef OSUM
    RED4L(s0) RED4L(s1) RED4L(s2) RED4L(s3)
    if (ln == 0){
      atomicAdd(out + (size_t)b*C3 + c0+0, s0*inv);
      atomicAdd(out + (size_t)b*C3 + c0+1, s1*inv);
      atomicAdd(out + (size_t)b*C3 + c0+2, s2*inv);
      atomicAdd(out + (size_t)b*C3 + c0+3, s3*inv);
    }
  }
}

extern "C" void kernel_launch(void* const* d_in, const int* in_sizes, int n_in,
                              void* d_out, int out_size, void* d_ws, size_t ws_size,
                              hipStream_t stream) {
  const float* x   = (const float*)d_in[0];
  const float* c1w = (const float*)d_in[1];
  const float* c1b = (const float*)d_in[2];
  const float* w1  = (const float*)d_in[3];
  const float* b1  = (const float*)d_in[4];
  const float* g1  = (const float*)d_in[5];
  const float* be1 = (const float*)d_in[6];
  const float* w2  = (const float*)d_in[7];
  const float* b2  = (const float*)d_in[8];
  const float* g2  = (const float*)d_in[9];
  const float* be2 = (const float*)d_in[10];
  const float* w3  = (const float*)d_in[11];
  const float* b3  = (const float*)d_in[12];
  const float* g3  = (const float*)d_in[13];
  const float* be3 = (const float*)d_in[14];
  float* ws  = (float*)d_ws;
  float* out = (float*)d_out;

  hipLaunchKernelGGL(k_patch,  dim3(32,NB), dim3(256), 0, stream, x, c1b, ws);
  hipLaunchKernelGGL(k_wB,     dim3(KPAD/256, NP), dim3(256), 0, stream, c1w, ws);
  hipLaunchKernelGGL(k_wt,     dim3((3*C3*C2+255)/256), dim3(256), 0, stream, w2, w3, ws);
  hipLaunchKernelGGL(k_gemm,   dim3(64,4,4), dim3(256), 0, stream, ws);
  hipLaunchKernelGGL(k_conv1f, dim3(8,NB), dim3(256), 0, stream, w1, b1, ws);
  hipLaunchKernelGGL(k_fin,    dim3(C1), dim3(256), 0, stream, ws+OFF_PS, ws+OFF_PQ, g1, be1, ws+OFF_S1, C1, NPART, 1.0/((double)NB*LEN1), (float*)nullptr);
  hipLaunchKernelGGL(k_bn1t,   dim3((LPAD1*C1/8 + 255)/256, NB), dim3(256), 0, stream, ws);
  hipLaunchKernelGGL(k_conv2m, dim3(4,NB), dim3(256), 0, stream, b2, ws);
  hipLaunchKernelGGL(k_fin,    dim3(C2), dim3(256), 0, stream, ws+OFF_PS, ws+OFF_PQ, g2, be2, ws+OFF_S2, C2, NPART2, 1.0/((double)NB*LEN2), (float*)nullptr);
  hipLaunchKernelGGL(k_p2bf,   dim3((LEN3*C2+3*C2+255)/256, NB), dim3(256), 0, stream, ws);
  hipLaunchKernelGGL(k_conv3s, dim3(4,NB), dim3(256), 0, stream, b3, ws);
  hipLaunchKernelGGL(k_fin,    dim3(C3), dim3(256), 0, stream, ws+OFF_PS, ws+OFF_PQ, g3, be3, ws+OFF_S3, C3, NPART, 1.0/((double)NB*LEN3), out);
  hipLaunchKernelGGL(k_out3,   dim3(4,NB), dim3(256), 0, stream, out, b3, ws);
}